// Round 1
// baseline (1246.426 us; speedup 1.0000x reference)
//
#include <hip/hip_runtime.h>

#define FRADIUS 1.3f
#define FN_INTR 128
#define FSTEP (2.0f * 1.3f / 128.0f)

// ---------- helpers ----------

// round-to-nearest-even f32 -> bf16, pack two into a u32 (lo, hi)
__device__ __forceinline__ unsigned int packbf2(float lo, float hi) {
    unsigned int ul = __float_as_uint(lo);
    unsigned int uh = __float_as_uint(hi);
    unsigned int rl = (ul + 0x7fffu + ((ul >> 16) & 1u)) >> 16;
    unsigned int rh = (uh + 0x7fffu + ((uh >> 16) & 1u)) & 0xffff0000u;
    return (rl & 0xffffu) | rh;
}

// acc[J] += act_row(bf16-pairs)[2*K2] @ w[2*K2][J]   (weights lane-uniform -> s_load)
template <int K2, int J>
__device__ __forceinline__ void dense_bf16(const unsigned int* hrow,
                                           const float* __restrict__ w,
                                           float* acc) {
#pragma unroll 2
    for (int k2 = 0; k2 < K2; ++k2) {
        unsigned int pv = hrow[k2];
        float a0 = __uint_as_float(pv << 16);
        float a1 = __uint_as_float(pv & 0xffff0000u);
        const float* wk = w + (2 * k2) * J;
#pragma unroll
        for (int j = 0; j < J; ++j) acc[j] = fmaf(a0, wk[j], acc[j]);
#pragma unroll
        for (int j = 0; j < J; ++j) acc[j] = fmaf(a1, wk[J + j], acc[j]);
    }
}

// acc[J] += act_row(f32)[K] @ w[K][J]
template <int K, int J>
__device__ __forceinline__ void dense_f32(const float* arow,
                                          const float* __restrict__ w,
                                          float* acc) {
#pragma unroll 2
    for (int k = 0; k < K; ++k) {
        float a = arow[k];
        const float* wk = w + k * J;
#pragma unroll
        for (int j = 0; j < J; ++j) acc[j] = fmaf(a, wk[j], acc[j]);
    }
}

// ---------- main fused kernel: 1 block = 1 ray (128 threads), 1 thread = 1 sample ----------

__global__ __launch_bounds__(128) void nerf_fused_kernel(
    const float* __restrict__ rays_o, const float* __restrict__ rays_d,
    const float* __restrict__ G1, const float* __restrict__ Fg,
    const float* __restrict__ s_w0, const float* __restrict__ s_w1,
    const float* __restrict__ s_w2, const float* __restrict__ c_w0,
    const float* __restrict__ c_w1, const float* __restrict__ c_w2,
    float* __restrict__ out) {
    // LDS: per-thread private rows (no cross-thread use until composite)
    __shared__ float bufA[128 * 33];          // fv(32) then cin(31); pad row to 33 (2-way bank alias = free)
    __shared__ unsigned int bufH[128 * 65];   // 128 bf16 = 64 u32 per row, pad to 65
    __shared__ float comp[128 * 4];           // alpha, sigmoid(rgb) for composite

    const int ray = blockIdx.x;
    const int s = threadIdx.x;  // sample index 0..127

    const float ox = rays_o[ray * 3 + 0], oy = rays_o[ray * 3 + 1], oz = rays_o[ray * 3 + 2];
    const float dx = rays_d[ray * 3 + 0], dy = rays_d[ray * 3 + 1], dz = rays_d[ray * 3 + 2];

    // ---- ray-AABB ----
    float sdx = (fabsf(dx) < 1e-9f) ? 1e-9f : dx;
    float sdy = (fabsf(dy) < 1e-9f) ? 1e-9f : dy;
    float sdz = (fabsf(dz) < 1e-9f) ? 1e-9f : dz;
    float t1x = (-FRADIUS - ox) / sdx, t2x = (FRADIUS - ox) / sdx;
    float t1y = (-FRADIUS - oy) / sdy, t2y = (FRADIUS - oy) / sdy;
    float t1z = (-FRADIUS - oz) / sdz, t2z = (FRADIUS - oz) / sdz;
    float tmin = fmaxf(fmaxf(fminf(t1x, t2x), fminf(t1y, t2y)), fminf(t1z, t2z));
    float tmax = fminf(fminf(fmaxf(t1x, t2x), fmaxf(t1y, t2y)), fmaxf(t1z, t2z));
    float tnear = fmaxf(tmin, 0.0f);
    float t = tnear + (float)s * FSTEP;
    bool maskb = (t < tmax) && (tmax > tnear);

    float px = ox + dx * t, py = oy + dy * t, pz = oz + dz * t;
    const float invR = 1.0f / FRADIUS;
    float cx = px * invR, cy = py * invR, cz = pz * invR;

    // ---- G1 trilinear (256^3 x 3) ----
    float fx = fminf(fmaxf((cx + 1.0f) * 0.5f * 255.0f, 0.0f), 255.0f);
    float fy = fminf(fmaxf((cy + 1.0f) * 0.5f * 255.0f, 0.0f), 255.0f);
    float fz = fminf(fmaxf((cz + 1.0f) * 0.5f * 255.0f, 0.0f), 255.0f);
    float x0f = floorf(fx), y0f = floorf(fy), z0f = floorf(fz);
    float wx = fx - x0f, wy = fy - y0f, wz = fz - z0f;
    int x0 = (int)x0f, y0 = (int)y0f, z0 = (int)z0f;
    int x1 = min(x0 + 1, 255), y1 = min(y0 + 1, 255), z1 = min(z0 + 1, 255);
    float g1x = 0.f, g1y = 0.f, g1z = 0.f;
    {
        float wz0 = 1.f - wz, wy0 = 1.f - wy, wx0 = 1.f - wx;
#pragma unroll
        for (int c = 0; c < 8; ++c) {
            int zz = (c & 4) ? z1 : z0;
            int yy = (c & 2) ? y1 : y0;
            int xx = (c & 1) ? x1 : x0;
            float w = ((c & 4) ? wz : wz0) * ((c & 2) ? wy : wy0) * ((c & 1) ? wx : wx0);
            int idx = (((zz << 8) | yy) << 8 | xx) * 3;
            g1x = fmaf(w, G1[idx + 0], g1x);
            g1y = fmaf(w, G1[idx + 1], g1y);
            g1z = fmaf(w, G1[idx + 2], g1z);
        }
    }

    // ---- Fg trilinear (64^3 x 32) ----
    float4 fv[8];
#pragma unroll
    for (int q = 0; q < 8; ++q) fv[q] = make_float4(0.f, 0.f, 0.f, 0.f);
    {
        float gfx = fminf(fmaxf((g1x + 1.0f) * 0.5f * 63.0f, 0.0f), 63.0f);
        float gfy = fminf(fmaxf((g1y + 1.0f) * 0.5f * 63.0f, 0.0f), 63.0f);
        float gfz = fminf(fmaxf((g1z + 1.0f) * 0.5f * 63.0f, 0.0f), 63.0f);
        float gx0f = floorf(gfx), gy0f = floorf(gfy), gz0f = floorf(gfz);
        float gwx = gfx - gx0f, gwy = gfy - gy0f, gwz = gfz - gz0f;
        int gx0 = (int)gx0f, gy0 = (int)gy0f, gz0 = (int)gz0f;
        int gx1 = min(gx0 + 1, 63), gy1 = min(gy0 + 1, 63), gz1 = min(gz0 + 1, 63);
        float wz0 = 1.f - gwz, wy0 = 1.f - gwy, wx0 = 1.f - gwx;
#pragma unroll
        for (int c = 0; c < 8; ++c) {
            int zz = (c & 4) ? gz1 : gz0;
            int yy = (c & 2) ? gy1 : gy0;
            int xx = (c & 1) ? gx1 : gx0;
            float w = ((c & 4) ? gwz : wz0) * ((c & 2) ? gwy : wy0) * ((c & 1) ? gwx : wx0);
            const float4* p = (const float4*)(Fg + (((((zz << 6) | yy) << 6) | xx) << 5));
#pragma unroll
            for (int q = 0; q < 8; ++q) {
                float4 v = p[q];
                fv[q].x = fmaf(w, v.x, fv[q].x);
                fv[q].y = fmaf(w, v.y, fv[q].y);
                fv[q].z = fmaf(w, v.z, fv[q].z);
                fv[q].w = fmaf(w, v.w, fv[q].w);
            }
        }
    }

    // stage fv into LDS (own row; no barrier needed)
    float* myA = &bufA[s * 33];
#pragma unroll
    for (int q = 0; q < 8; ++q) {
        myA[q * 4 + 0] = fv[q].x;
        myA[q * 4 + 1] = fv[q].y;
        myA[q * 4 + 2] = fv[q].z;
        myA[q * 4 + 3] = fv[q].w;
    }

    unsigned int* myH = &bufH[s * 65];

    // ---- sigma MLP: 32 -> 128 -> 128 -> 16 ----
    {
        float acc[128];
#pragma unroll
        for (int j = 0; j < 128; ++j) acc[j] = 0.f;
        dense_f32<32, 128>(myA, s_w0, acc);
#pragma unroll
        for (int k2 = 0; k2 < 64; ++k2)
            myH[k2] = packbf2(fmaxf(acc[2 * k2], 0.f), fmaxf(acc[2 * k2 + 1], 0.f));
    }
    {
        float acc[128];
#pragma unroll
        for (int j = 0; j < 128; ++j) acc[j] = 0.f;
        dense_bf16<64, 128>(myH, s_w1, acc);
#pragma unroll
        for (int k2 = 0; k2 < 64; ++k2)
            myH[k2] = packbf2(fmaxf(acc[2 * k2], 0.f), fmaxf(acc[2 * k2 + 1], 0.f));
    }
    float sig[16];
#pragma unroll
    for (int j = 0; j < 16; ++j) sig[j] = 0.f;
    dense_bf16<64, 16>(myH, s_w2, sig);

    float sigma = maskb ? fmaxf(sig[0], 0.f) : 0.f;
    float alpha = 1.0f - __expf(-sigma * FSTEP);

    // ---- SH deg-4 encoding of normalized dir ----
    {
        float inv = rsqrtf(dx * dx + dy * dy + dz * dz);
        float nx = dx * inv, ny = dy * inv, nz = dz * inv;
        float nx2 = nx * nx, ny2 = ny * ny, nz2 = nz * nz;
        float nxy = nx * ny, nyz = ny * nz, nxz = nx * nz;
        myA[0] = 0.28209479177387814f;
        myA[1] = -0.48860251190291987f * ny;
        myA[2] = 0.48860251190291987f * nz;
        myA[3] = -0.48860251190291987f * nx;
        myA[4] = 1.0925484305920792f * nxy;
        myA[5] = -1.0925484305920792f * nyz;
        myA[6] = 0.94617469575756f * nz2 - 0.31539156525252f;
        myA[7] = -1.0925484305920792f * nxz;
        myA[8] = 0.5462742152960396f * (nx2 - ny2);
        myA[9] = 0.5900435899266435f * ny * (-3.0f * nx2 + ny2);
        myA[10] = 2.890611442640554f * nxy * nz;
        myA[11] = 0.4570457994644657f * ny * (1.0f - 5.0f * nz2);
        myA[12] = 0.3731763325901154f * nz * (5.0f * nz2 - 3.0f);
        myA[13] = 0.4570457994644657f * nx * (1.0f - 5.0f * nz2);
        myA[14] = 1.445305721320277f * nz * (nx2 - ny2);
        myA[15] = 0.5900435899266435f * nx * (-nx2 + 3.0f * ny2);
#pragma unroll
        for (int i = 0; i < 15; ++i) myA[16 + i] = sig[1 + i];
    }

    // ---- color MLP: 31 -> 64 -> 64 -> 3 ----
    float c2[64];
    {
        float acc[64];
#pragma unroll
        for (int j = 0; j < 64; ++j) acc[j] = 0.f;
        dense_f32<31, 64>(myA, c_w0, acc);
#pragma unroll
        for (int k2 = 0; k2 < 32; ++k2)
            myH[k2] = packbf2(fmaxf(acc[2 * k2], 0.f), fmaxf(acc[2 * k2 + 1], 0.f));
    }
#pragma unroll
    for (int j = 0; j < 64; ++j) c2[j] = 0.f;
    dense_bf16<32, 64>(myH, c_w1, c2);

    float rr = 0.f, rg = 0.f, rb = 0.f;
#pragma unroll
    for (int k = 0; k < 64; ++k) {
        float v = fmaxf(c2[k], 0.f);
        rr = fmaf(v, c_w2[k * 3 + 0], rr);
        rg = fmaf(v, c_w2[k * 3 + 1], rg);
        rb = fmaf(v, c_w2[k * 3 + 2], rb);
    }

    comp[s * 4 + 0] = alpha;
    comp[s * 4 + 1] = 1.0f / (1.0f + __expf(-rr));
    comp[s * 4 + 2] = 1.0f / (1.0f + __expf(-rg));
    comp[s * 4 + 3] = 1.0f / (1.0f + __expf(-rb));

    __syncthreads();

    // ---- composite: wave 0 does a 64-lane parallel scan over 128 samples ----
    if (s < 64) {
        int lane = s;
        float a_lo = comp[lane * 4 + 0];
        float a_hi = comp[(lane + 64) * 4 + 0];
        float rl0 = comp[lane * 4 + 1], rl1 = comp[lane * 4 + 2], rl2 = comp[lane * 4 + 3];
        float rh0 = comp[(lane + 64) * 4 + 1], rh1 = comp[(lane + 64) * 4 + 2], rh2 = comp[(lane + 64) * 4 + 3];

        float m_lo = 1.0f - a_lo + 1e-10f;
        float m_hi = 1.0f - a_hi + 1e-10f;

        // inclusive scans (multiplicative)
        float p = m_lo;
#pragma unroll
        for (int off = 1; off < 64; off <<= 1) {
            float q = __shfl_up(p, off, 64);
            if (lane >= off) p *= q;
        }
        float ph = m_hi;
#pragma unroll
        for (int off = 1; off < 64; off <<= 1) {
            float q = __shfl_up(ph, off, 64);
            if (lane >= off) ph *= q;
        }
        float total_lo = __shfl(p, 63, 64);
        float e_lo = __shfl_up(p, 1, 64);
        if (lane == 0) e_lo = 1.0f;
        float e_hi = __shfl_up(ph, 1, 64);
        if (lane == 0) e_hi = 1.0f;
        e_hi *= total_lo;

        float w_lo = a_lo * e_lo;
        float w_hi = a_hi * e_hi;

        float sr = w_lo * rl0 + w_hi * rh0;
        float sg = w_lo * rl1 + w_hi * rh1;
        float sb = w_lo * rl2 + w_hi * rh2;
        float sw = w_lo + w_hi;
#pragma unroll
        for (int off = 32; off >= 1; off >>= 1) {
            sr += __shfl_xor(sr, off, 64);
            sg += __shfl_xor(sg, off, 64);
            sb += __shfl_xor(sb, off, 64);
            sw += __shfl_xor(sw, off, 64);
        }
        if (lane == 0) {
            float bg = 1.0f - sw;
            out[ray * 3 + 0] = sr + bg;
            out[ray * 3 + 1] = sg + bg;
            out[ray * 3 + 2] = sb + bg;
        }
    }
}

extern "C" void kernel_launch(void* const* d_in, const int* in_sizes, int n_in,
                              void* d_out, int out_size, void* d_ws, size_t ws_size,
                              hipStream_t stream) {
    const float* rays_o = (const float*)d_in[0];
    const float* rays_d = (const float*)d_in[1];
    const float* G1 = (const float*)d_in[2];
    const float* Fg = (const float*)d_in[3];
    const float* s_w0 = (const float*)d_in[4];
    const float* s_w1 = (const float*)d_in[5];
    const float* s_w2 = (const float*)d_in[6];
    const float* c_w0 = (const float*)d_in[7];
    const float* c_w1 = (const float*)d_in[8];
    const float* c_w2 = (const float*)d_in[9];
    float* out = (float*)d_out;

    const int B = in_sizes[0] / 3;  // 8192 rays
    nerf_fused_kernel<<<dim3(B), dim3(128), 0, stream>>>(
        rays_o, rays_d, G1, Fg, s_w0, s_w1, s_w2, c_w0, c_w1, c_w2, out);
}

// Round 2
// 203.830 us; speedup vs baseline: 6.1150x; 6.1150x over previous
//
#include <hip/hip_runtime.h>
#include <hip/hip_bf16.h>

#define FRADIUS 1.3f
#define FSTEP (2.0f * 1.3f / 128.0f)

typedef __attribute__((ext_vector_type(8))) short short8;
typedef __attribute__((ext_vector_type(4))) float f32x4;

#define MFMA16(a, b, c) __builtin_amdgcn_mfma_f32_16x16x32_bf16((a), (b), (c), 0, 0, 0)

// pack two f32 -> bf16x2 in a dword (RNE); low 16 bits = a
__device__ __forceinline__ unsigned pk2(float a, float b) {
    __hip_bfloat162 h = __float22bfloat162_rn(make_float2(a, b));
    union { __hip_bfloat162 h; unsigned u; } cv;
    cv.h = h;
    return cv.u;
}

// ---------------- weight prep: build MFMA A-operand fragments in d_ws ----------------
// Fragment layout (1 KiB each): lane l holds W[k = kt*32 + (l>>4)*8 + j][n = nt*16 + (l&15)],
// j = 0..7, packed bf16 pairs -> 4 dwords at frag_base + l*16.
// frag ids: s0:0..7 (nt,kt=0) | s1:8..39 (nt*4+kt) | s2:40..43 (kt) | c0:44..47 (nt)
//           c1:48..55 (nt*2+kt) | c2:56..57 (kt)
__global__ void prep_weights_kernel(const float* __restrict__ s_w0, const float* __restrict__ s_w1,
                                    const float* __restrict__ s_w2, const float* __restrict__ c_w0,
                                    const float* __restrict__ c_w1, const float* __restrict__ c_w2,
                                    uint4* __restrict__ ws) {
    int fid = blockIdx.x;
    int l = threadIdx.x;
    int hi = l >> 4, lo = l & 15;
    int nt, kt;
    if (fid < 8)       { nt = fid; kt = 0; }
    else if (fid < 40) { int f = fid - 8;  nt = f >> 2; kt = f & 3; }
    else if (fid < 44) { nt = 0; kt = fid - 40; }
    else if (fid < 48) { nt = fid - 44; kt = 0; }
    else if (fid < 56) { int f = fid - 48; nt = f >> 1; kt = f & 1; }
    else               { nt = 0; kt = fid - 56; }
    int n = nt * 16 + lo;
    float v[8];
#pragma unroll
    for (int j = 0; j < 8; ++j) {
        int k = kt * 32 + hi * 8 + j;
        float x;
        if (fid < 8)       x = s_w0[k * 128 + n];
        else if (fid < 40) x = s_w1[k * 128 + n];
        else if (fid < 44) x = s_w2[k * 16 + n];
        else if (fid < 48) x = (k < 16) ? c_w0[k * 64 + n]
                               : ((k == 16) ? 0.0f : c_w0[(k - 1) * 64 + n]);  // zero row: sig[0] unused
        else if (fid < 56) x = c_w1[k * 64 + n];
        else               x = (n < 3) ? c_w2[k * 3 + n] : 0.0f;
        v[j] = x;
    }
    uint4 u;
    u.x = pk2(v[0], v[1]); u.y = pk2(v[2], v[3]);
    u.z = pk2(v[4], v[5]); u.w = pk2(v[6], v[7]);
    ws[fid * 64 + l] = u;
}

// ---------------- main fused kernel: 1 block = 1 ray (128 thd = 2 waves) ----------------
__global__ __launch_bounds__(128) void nerf_mfma_kernel(
    const float* __restrict__ rays_o, const float* __restrict__ rays_d,
    const float* __restrict__ G1, const float* __restrict__ Fg,
    const short8* __restrict__ wsf, float* __restrict__ out) {

    // per-wave arenas; all row strides are multiples of 16 B (b128-legal), <=2-way banks
    __shared__ __align__(16) __hip_bfloat16 fvb[2][64][40];    // fv rows (32 used), 80 B stride
    __shared__ __align__(16) __hip_bfloat16 scr[2][32][136];   // activation staging, 272 B stride
    __shared__ __align__(16) __hip_bfloat16 sgm[2][2][16][24]; // raw sig[0..15] per point, 48 B stride
    __shared__ __align__(16) float comp[128][4];               // mask-flag then {alpha, rgb_sigmoid}

    const int ray = blockIdx.x;
    const int tid = threadIdx.x;
    const int w = tid >> 6;
    const int lane = tid & 63;
    const int hi = lane >> 4, lo = lane & 15;
    const int s = tid;  // sample 0..127

    const float ox = rays_o[ray * 3 + 0], oy = rays_o[ray * 3 + 1], oz = rays_o[ray * 3 + 2];
    const float dx = rays_d[ray * 3 + 0], dy = rays_d[ray * 3 + 1], dz = rays_d[ray * 3 + 2];

    // ---- phase 1: ray march + two trilinear samples (1 thread = 1 sample) ----
    float sdx = (fabsf(dx) < 1e-9f) ? 1e-9f : dx;
    float sdy = (fabsf(dy) < 1e-9f) ? 1e-9f : dy;
    float sdz = (fabsf(dz) < 1e-9f) ? 1e-9f : dz;
    float t1x = (-FRADIUS - ox) / sdx, t2x = (FRADIUS - ox) / sdx;
    float t1y = (-FRADIUS - oy) / sdy, t2y = (FRADIUS - oy) / sdy;
    float t1z = (-FRADIUS - oz) / sdz, t2z = (FRADIUS - oz) / sdz;
    float tmin = fmaxf(fmaxf(fminf(t1x, t2x), fminf(t1y, t2y)), fminf(t1z, t2z));
    float tmax = fminf(fminf(fmaxf(t1x, t2x), fmaxf(t1y, t2y)), fmaxf(t1z, t2z));
    float tnear = fmaxf(tmin, 0.0f);
    float t = tnear + (float)s * FSTEP;
    bool maskb = (t < tmax) && (tmax > tnear);

    float px = ox + dx * t, py = oy + dy * t, pz = oz + dz * t;
    const float invR = 1.0f / FRADIUS;
    float cx = px * invR, cy = py * invR, cz = pz * invR;

    // G1 trilinear (256^3 x 3)
    float fx = fminf(fmaxf((cx + 1.0f) * 0.5f * 255.0f, 0.0f), 255.0f);
    float fy = fminf(fmaxf((cy + 1.0f) * 0.5f * 255.0f, 0.0f), 255.0f);
    float fz = fminf(fmaxf((cz + 1.0f) * 0.5f * 255.0f, 0.0f), 255.0f);
    float x0f = floorf(fx), y0f = floorf(fy), z0f = floorf(fz);
    float wx = fx - x0f, wy = fy - y0f, wz = fz - z0f;
    int x0 = (int)x0f, y0 = (int)y0f, z0 = (int)z0f;
    int x1 = min(x0 + 1, 255), y1 = min(y0 + 1, 255), z1 = min(z0 + 1, 255);
    float g1x = 0.f, g1y = 0.f, g1z = 0.f;
    {
        float wz0 = 1.f - wz, wy0 = 1.f - wy, wx0 = 1.f - wx;
#pragma unroll
        for (int c = 0; c < 8; ++c) {
            int zz = (c & 4) ? z1 : z0;
            int yy = (c & 2) ? y1 : y0;
            int xx = (c & 1) ? x1 : x0;
            float wgt = ((c & 4) ? wz : wz0) * ((c & 2) ? wy : wy0) * ((c & 1) ? wx : wx0);
            int idx = (((zz << 8) | yy) << 8 | xx) * 3;
            g1x = fmaf(wgt, G1[idx + 0], g1x);
            g1y = fmaf(wgt, G1[idx + 1], g1y);
            g1z = fmaf(wgt, G1[idx + 2], g1z);
        }
    }

    // Fg trilinear (64^3 x 32)
    float4 fvv[8];
#pragma unroll
    for (int q = 0; q < 8; ++q) fvv[q] = make_float4(0.f, 0.f, 0.f, 0.f);
    {
        float gfx = fminf(fmaxf((g1x + 1.0f) * 0.5f * 63.0f, 0.0f), 63.0f);
        float gfy = fminf(fmaxf((g1y + 1.0f) * 0.5f * 63.0f, 0.0f), 63.0f);
        float gfz = fminf(fmaxf((g1z + 1.0f) * 0.5f * 63.0f, 0.0f), 63.0f);
        float gx0f = floorf(gfx), gy0f = floorf(gfy), gz0f = floorf(gfz);
        float gwx = gfx - gx0f, gwy = gfy - gy0f, gwz = gfz - gz0f;
        int gx0 = (int)gx0f, gy0 = (int)gy0f, gz0 = (int)gz0f;
        int gx1 = min(gx0 + 1, 63), gy1 = min(gy0 + 1, 63), gz1 = min(gz0 + 1, 63);
        float wz0 = 1.f - gwz, wy0 = 1.f - gwy, wx0 = 1.f - gwx;
#pragma unroll
        for (int c = 0; c < 8; ++c) {
            int zz = (c & 4) ? gz1 : gz0;
            int yy = (c & 2) ? gy1 : gy0;
            int xx = (c & 1) ? gx1 : gx0;
            float wgt = ((c & 4) ? gwz : wz0) * ((c & 2) ? gwy : wy0) * ((c & 1) ? gwx : wx0);
            const float4* p = (const float4*)(Fg + (((((zz << 6) | yy) << 6) | xx) << 5));
#pragma unroll
            for (int q = 0; q < 8; ++q) {
                float4 v = p[q];
                fvv[q].x = fmaf(wgt, v.x, fvv[q].x);
                fvv[q].y = fmaf(wgt, v.y, fvv[q].y);
                fvv[q].z = fmaf(wgt, v.z, fvv[q].z);
                fvv[q].w = fmaf(wgt, v.w, fvv[q].w);
            }
        }
    }

    comp[s][0] = maskb ? 1.0f : 0.0f;  // mask flag (overwritten by alpha later)

    // stage fv row as bf16 (own row; same-wave readers, no barrier)
    {
        uint4* rowp = (uint4*)&fvb[w][lane][0];
#pragma unroll
        for (int q = 0; q < 4; ++q) {
            uint4 u;
            u.x = pk2(fvv[2 * q].x, fvv[2 * q].y);
            u.y = pk2(fvv[2 * q].z, fvv[2 * q].w);
            u.z = pk2(fvv[2 * q + 1].x, fvv[2 * q + 1].y);
            u.w = pk2(fvv[2 * q + 1].z, fvv[2 * q + 1].w);
            rowp[q] = u;
        }
    }

    // ---- SH deg-4 enc (per-ray uniform); lane keeps its k-slice as a B-frag half ----
    short8 encfrag;
    {
        float inv = rsqrtf(dx * dx + dy * dy + dz * dz);
        float nx = dx * inv, ny = dy * inv, nz = dz * inv;
        float nx2 = nx * nx, ny2 = ny * ny, nz2 = nz * nz;
        float nxy = nx * ny, nyz = ny * nz, nxz = nx * nz;
        float e0 = 0.28209479177387814f;
        float e1 = -0.48860251190291987f * ny;
        float e2 = 0.48860251190291987f * nz;
        float e3 = -0.48860251190291987f * nx;
        float e4 = 1.0925484305920792f * nxy;
        float e5 = -1.0925484305920792f * nyz;
        float e6 = 0.94617469575756f * nz2 - 0.31539156525252f;
        float e7 = -1.0925484305920792f * nxz;
        float e8 = 0.5462742152960396f * (nx2 - ny2);
        float e9 = 0.5900435899266435f * ny * (-3.0f * nx2 + ny2);
        float e10 = 2.890611442640554f * nxy * nz;
        float e11 = 0.4570457994644657f * ny * (1.0f - 5.0f * nz2);
        float e12 = 0.3731763325901154f * nz * (5.0f * nz2 - 3.0f);
        float e13 = 0.4570457994644657f * nx * (1.0f - 5.0f * nz2);
        float e14 = 1.445305721320277f * nz * (nx2 - ny2);
        float e15 = 0.5900435899266435f * nx * (-nx2 + 3.0f * ny2);
        unsigned l0 = pk2(e0, e1), l1 = pk2(e2, e3), l2 = pk2(e4, e5), l3 = pk2(e6, e7);
        unsigned h0 = pk2(e8, e9), h1 = pk2(e10, e11), h2 = pk2(e12, e13), h3 = pk2(e14, e15);
        union { unsigned u[4]; short8 v; } eu;
        eu.u[0] = (hi & 1) ? h0 : l0;
        eu.u[1] = (hi & 1) ? h1 : l1;
        eu.u[2] = (hi & 1) ? h2 : l2;
        eu.u[3] = (hi & 1) ? h3 : l3;
        encfrag = eu.v;
    }
    const bool isEnc = (hi < 2);
    const f32x4 fz4 = {0.f, 0.f, 0.f, 0.f};

    // ---- phase 2: MFMA MLP chain; wave-private, M=32 per m-pair ----
    for (int mp = 0; mp < 2; ++mp) {
        const int rbase = mp * 32;

        // s0: 32 -> 128
        short8 x0[2];
#pragma unroll
        for (int tt = 0; tt < 2; ++tt)
            x0[tt] = *(const short8*)&fvb[w][rbase + tt * 16 + lo][hi * 8];
        f32x4 acc[2][8];
#pragma unroll
        for (int tt = 0; tt < 2; ++tt)
#pragma unroll
            for (int nt = 0; nt < 8; ++nt) acc[tt][nt] = fz4;
        {
            short8 wv[8];
#pragma unroll
            for (int nt = 0; nt < 8; ++nt) wv[nt] = wsf[(0 + nt) * 64 + lane];
#pragma unroll
            for (int nt = 0; nt < 8; ++nt)
#pragma unroll
                for (int tt = 0; tt < 2; ++tt)
                    acc[tt][nt] = MFMA16(wv[nt], x0[tt], acc[tt][nt]);
        }
#pragma unroll
        for (int tt = 0; tt < 2; ++tt)
#pragma unroll
            for (int nt = 0; nt < 8; ++nt) {
                f32x4 v = acc[tt][nt];
                uint2 pkv;
                pkv.x = pk2(fmaxf(v[0], 0.f), fmaxf(v[1], 0.f));
                pkv.y = pk2(fmaxf(v[2], 0.f), fmaxf(v[3], 0.f));
                *(uint2*)&scr[w][tt * 16 + lo][nt * 16 + hi * 4] = pkv;
            }

        // s1: 128 -> 128
        f32x4 acc1[2][8];
#pragma unroll
        for (int tt = 0; tt < 2; ++tt)
#pragma unroll
            for (int nt = 0; nt < 8; ++nt) acc1[tt][nt] = fz4;
#pragma unroll
        for (int kt = 0; kt < 4; ++kt) {
            short8 xv[2];
#pragma unroll
            for (int tt = 0; tt < 2; ++tt)
                xv[tt] = *(const short8*)&scr[w][tt * 16 + lo][kt * 32 + hi * 8];
            short8 wv[8];
#pragma unroll
            for (int nt = 0; nt < 8; ++nt) wv[nt] = wsf[(8 + nt * 4 + kt) * 64 + lane];
#pragma unroll
            for (int nt = 0; nt < 8; ++nt)
#pragma unroll
                for (int tt = 0; tt < 2; ++tt)
                    acc1[tt][nt] = MFMA16(wv[nt], xv[tt], acc1[tt][nt]);
        }
#pragma unroll
        for (int tt = 0; tt < 2; ++tt)
#pragma unroll
            for (int nt = 0; nt < 8; ++nt) {
                f32x4 v = acc1[tt][nt];
                uint2 pkv;
                pkv.x = pk2(fmaxf(v[0], 0.f), fmaxf(v[1], 0.f));
                pkv.y = pk2(fmaxf(v[2], 0.f), fmaxf(v[3], 0.f));
                *(uint2*)&scr[w][tt * 16 + lo][nt * 16 + hi * 4] = pkv;
            }

        // s2: 128 -> 16 (raw outputs)
        f32x4 accS[2];
#pragma unroll
        for (int tt = 0; tt < 2; ++tt) accS[tt] = fz4;
#pragma unroll
        for (int kt = 0; kt < 4; ++kt) {
            short8 xv[2];
#pragma unroll
            for (int tt = 0; tt < 2; ++tt)
                xv[tt] = *(const short8*)&scr[w][tt * 16 + lo][kt * 32 + hi * 8];
            short8 wv = wsf[(40 + kt) * 64 + lane];
#pragma unroll
            for (int tt = 0; tt < 2; ++tt)
                accS[tt] = MFMA16(wv, xv[tt], accS[tt]);
        }
        float alphaR[2];
#pragma unroll
        for (int tt = 0; tt < 2; ++tt) {
            f32x4 v = accS[tt];
            uint2 pkv;
            pkv.x = pk2(v[0], v[1]);
            pkv.y = pk2(v[2], v[3]);
            *(uint2*)&sgm[w][tt][lo][hi * 4] = pkv;
            float mk = comp[w * 64 + rbase + tt * 16 + lo][0];
            float sg = fmaxf(v[0], 0.f);
            alphaR[tt] = (mk != 0.0f) ? 1.0f - __expf(-sg * FSTEP) : 0.0f;
        }

        // c0: 32(31) -> 64 ; B-frag = [enc | sig]
        short8 xc[2];
#pragma unroll
        for (int tt = 0; tt < 2; ++tt) {
            short8 sv = *(const short8*)&sgm[w][tt][lo][(hi & 1) * 8];
            xc[tt] = isEnc ? encfrag : sv;
        }
        f32x4 accC[2][4];
#pragma unroll
        for (int tt = 0; tt < 2; ++tt)
#pragma unroll
            for (int nt = 0; nt < 4; ++nt) accC[tt][nt] = fz4;
        {
            short8 wv[4];
#pragma unroll
            for (int nt = 0; nt < 4; ++nt) wv[nt] = wsf[(44 + nt) * 64 + lane];
#pragma unroll
            for (int nt = 0; nt < 4; ++nt)
#pragma unroll
                for (int tt = 0; tt < 2; ++tt)
                    accC[tt][nt] = MFMA16(wv[nt], xc[tt], accC[tt][nt]);
        }
#pragma unroll
        for (int tt = 0; tt < 2; ++tt)
#pragma unroll
            for (int nt = 0; nt < 4; ++nt) {
                f32x4 v = accC[tt][nt];
                uint2 pkv;
                pkv.x = pk2(fmaxf(v[0], 0.f), fmaxf(v[1], 0.f));
                pkv.y = pk2(fmaxf(v[2], 0.f), fmaxf(v[3], 0.f));
                *(uint2*)&scr[w][tt * 16 + lo][nt * 16 + hi * 4] = pkv;
            }

        // c1: 64 -> 64
        f32x4 accD[2][4];
#pragma unroll
        for (int tt = 0; tt < 2; ++tt)
#pragma unroll
            for (int nt = 0; nt < 4; ++nt) accD[tt][nt] = fz4;
#pragma unroll
        for (int kt = 0; kt < 2; ++kt) {
            short8 xv[2];
#pragma unroll
            for (int tt = 0; tt < 2; ++tt)
                xv[tt] = *(const short8*)&scr[w][tt * 16 + lo][kt * 32 + hi * 8];
            short8 wv[4];
#pragma unroll
            for (int nt = 0; nt < 4; ++nt) wv[nt] = wsf[(48 + nt * 2 + kt) * 64 + lane];
#pragma unroll
            for (int nt = 0; nt < 4; ++nt)
#pragma unroll
                for (int tt = 0; tt < 2; ++tt)
                    accD[tt][nt] = MFMA16(wv[nt], xv[tt], accD[tt][nt]);
        }
#pragma unroll
        for (int tt = 0; tt < 2; ++tt)
#pragma unroll
            for (int nt = 0; nt < 4; ++nt) {
                f32x4 v = accD[tt][nt];
                uint2 pkv;
                pkv.x = pk2(fmaxf(v[0], 0.f), fmaxf(v[1], 0.f));
                pkv.y = pk2(fmaxf(v[2], 0.f), fmaxf(v[3], 0.f));
                *(uint2*)&scr[w][tt * 16 + lo][nt * 16 + hi * 4] = pkv;
            }

        // c2: 64 -> 16(3)
        f32x4 accF[2];
#pragma unroll
        for (int tt = 0; tt < 2; ++tt) accF[tt] = fz4;
#pragma unroll
        for (int kt = 0; kt < 2; ++kt) {
            short8 xv[2];
#pragma unroll
            for (int tt = 0; tt < 2; ++tt)
                xv[tt] = *(const short8*)&scr[w][tt * 16 + lo][kt * 32 + hi * 8];
            short8 wv = wsf[(56 + kt) * 64 + lane];
#pragma unroll
            for (int tt = 0; tt < 2; ++tt)
                accF[tt] = MFMA16(wv, xv[tt], accF[tt]);
        }
        if (hi == 0) {
#pragma unroll
            for (int tt = 0; tt < 2; ++tt) {
                int p = w * 64 + rbase + tt * 16 + lo;
                f32x4 v = accF[tt];
                float4 cv;
                cv.x = alphaR[tt];
                cv.y = 1.0f / (1.0f + __expf(-v[0]));
                cv.z = 1.0f / (1.0f + __expf(-v[1]));
                cv.w = 1.0f / (1.0f + __expf(-v[2]));
                *(float4*)&comp[p][0] = cv;
            }
        }
    }

    __syncthreads();

    // ---- phase 3: composite (wave 0: 64-lane scan over 128 samples) ----
    if (tid < 64) {
        const float4* c4 = (const float4*)comp;
        float4 vl = c4[tid];
        float4 vh = c4[tid + 64];
        float a_lo = vl.x, a_hi = vh.x;
        float m_lo = 1.0f - a_lo + 1e-10f;
        float m_hi = 1.0f - a_hi + 1e-10f;

        float p = m_lo;
#pragma unroll
        for (int off = 1; off < 64; off <<= 1) {
            float q = __shfl_up(p, off, 64);
            if (tid >= off) p *= q;
        }
        float ph = m_hi;
#pragma unroll
        for (int off = 1; off < 64; off <<= 1) {
            float q = __shfl_up(ph, off, 64);
            if (tid >= off) ph *= q;
        }
        float total_lo = __shfl(p, 63, 64);
        float e_lo = __shfl_up(p, 1, 64);
        if (tid == 0) e_lo = 1.0f;
        float e_hi = __shfl_up(ph, 1, 64);
        if (tid == 0) e_hi = 1.0f;
        e_hi *= total_lo;

        float w_lo = a_lo * e_lo;
        float w_hi = a_hi * e_hi;

        float sr = w_lo * vl.y + w_hi * vh.y;
        float sg = w_lo * vl.z + w_hi * vh.z;
        float sb = w_lo * vl.w + w_hi * vh.w;
        float sw = w_lo + w_hi;
#pragma unroll
        for (int off = 32; off >= 1; off >>= 1) {
            sr += __shfl_xor(sr, off, 64);
            sg += __shfl_xor(sg, off, 64);
            sb += __shfl_xor(sb, off, 64);
            sw += __shfl_xor(sw, off, 64);
        }
        if (tid == 0) {
            float bg = 1.0f - sw;
            out[ray * 3 + 0] = sr + bg;
            out[ray * 3 + 1] = sg + bg;
            out[ray * 3 + 2] = sb + bg;
        }
    }
}

extern "C" void kernel_launch(void* const* d_in, const int* in_sizes, int n_in,
                              void* d_out, int out_size, void* d_ws, size_t ws_size,
                              hipStream_t stream) {
    const float* rays_o = (const float*)d_in[0];
    const float* rays_d = (const float*)d_in[1];
    const float* G1 = (const float*)d_in[2];
    const float* Fg = (const float*)d_in[3];
    const float* s_w0 = (const float*)d_in[4];
    const float* s_w1 = (const float*)d_in[5];
    const float* s_w2 = (const float*)d_in[6];
    const float* c_w0 = (const float*)d_in[7];
    const float* c_w1 = (const float*)d_in[8];
    const float* c_w2 = (const float*)d_in[9];
    float* out = (float*)d_out;

    const int B = in_sizes[0] / 3;  // 8192 rays

    prep_weights_kernel<<<dim3(58), dim3(64), 0, stream>>>(s_w0, s_w1, s_w2, c_w0, c_w1, c_w2,
                                                           (uint4*)d_ws);
    nerf_mfma_kernel<<<dim3(B), dim3(128), 0, stream>>>(
        rays_o, rays_d, G1, Fg, (const short8*)d_ws, out);
}

// Round 3
// 188.194 us; speedup vs baseline: 6.6231x; 1.0831x over previous
//
#include <hip/hip_runtime.h>
#include <hip/hip_bf16.h>

#define FRADIUS 1.3f
#define FSTEP (2.0f * 1.3f / 128.0f)

typedef __attribute__((ext_vector_type(8))) short short8;
typedef __attribute__((ext_vector_type(4))) float f32x4;

#define MFMA16(a, b, c) __builtin_amdgcn_mfma_f32_16x16x32_bf16((a), (b), (c), 0, 0, 0)

// pack two f32 -> bf16x2 in a dword (RNE); low 16 bits = a
__device__ __forceinline__ unsigned pk2(float a, float b) {
    __hip_bfloat162 h = __float22bfloat162_rn(make_float2(a, b));
    union { __hip_bfloat162 h; unsigned u; } cv;
    cv.h = h;
    return cv.u;
}

// shared ray-AABB so sample/mlp kernels agree bit-exactly
__device__ __forceinline__ void ray_aabb(float ox, float oy, float oz,
                                         float dx, float dy, float dz,
                                         float& tnear, float& tmax) {
    float sdx = (fabsf(dx) < 1e-9f) ? 1e-9f : dx;
    float sdy = (fabsf(dy) < 1e-9f) ? 1e-9f : dy;
    float sdz = (fabsf(dz) < 1e-9f) ? 1e-9f : dz;
    float t1x = (-FRADIUS - ox) / sdx, t2x = (FRADIUS - ox) / sdx;
    float t1y = (-FRADIUS - oy) / sdy, t2y = (FRADIUS - oy) / sdy;
    float t1z = (-FRADIUS - oz) / sdz, t2z = (FRADIUS - oz) / sdz;
    float tmin = fmaxf(fmaxf(fminf(t1x, t2x), fminf(t1y, t2y)), fminf(t1z, t2z));
    tmax = fminf(fminf(fmaxf(t1x, t2x), fmaxf(t1y, t2y)), fmaxf(t1z, t2z));
    tnear = fmaxf(tmin, 0.0f);
}

// ---------------- weight prep: build MFMA A-operand fragments in d_ws ----------------
// Fragment layout (1 KiB each): lane l holds W[k = kt*32 + (l>>4)*8 + j][n = nt*16 + (l&15)],
// j = 0..7, packed bf16 pairs -> 4 dwords at frag_base + l*16.
// frag ids: s0:0..7 (nt,kt=0) | s1:8..39 (nt*4+kt) | s2:40..43 (kt) | c0:44..47 (nt)
//           c1:48..55 (nt*2+kt) | c2:56..57 (kt)
__global__ void prep_weights_kernel(const float* __restrict__ s_w0, const float* __restrict__ s_w1,
                                    const float* __restrict__ s_w2, const float* __restrict__ c_w0,
                                    const float* __restrict__ c_w1, const float* __restrict__ c_w2,
                                    uint4* __restrict__ ws) {
    int fid = blockIdx.x;
    int l = threadIdx.x;
    int hi = l >> 4, lo = l & 15;
    int nt, kt;
    if (fid < 8)       { nt = fid; kt = 0; }
    else if (fid < 40) { int f = fid - 8;  nt = f >> 2; kt = f & 3; }
    else if (fid < 44) { nt = 0; kt = fid - 40; }
    else if (fid < 48) { nt = fid - 44; kt = 0; }
    else if (fid < 56) { int f = fid - 48; nt = f >> 1; kt = f & 1; }
    else               { nt = 0; kt = fid - 56; }
    int n = nt * 16 + lo;
    float v[8];
#pragma unroll
    for (int j = 0; j < 8; ++j) {
        int k = kt * 32 + hi * 8 + j;
        float x;
        if (fid < 8)       x = s_w0[k * 128 + n];
        else if (fid < 40) x = s_w1[k * 128 + n];
        else if (fid < 44) x = s_w2[k * 16 + n];
        else if (fid < 48) x = (k < 16) ? c_w0[k * 64 + n]
                               : ((k == 16) ? 0.0f : c_w0[(k - 1) * 64 + n]);  // zero row: sig[0] unused
        else if (fid < 56) x = c_w1[k * 64 + n];
        else               x = (n < 3) ? c_w2[k * 3 + n] : 0.0f;
        v[j] = x;
    }
    uint4 u;
    u.x = pk2(v[0], v[1]); u.y = pk2(v[2], v[3]);
    u.z = pk2(v[4], v[5]); u.w = pk2(v[6], v[7]);
    ws[fid * 64 + l] = u;
}

// ---------------- kernel A: gather phase (1 thread = 1 sample point) ----------------
__global__ __launch_bounds__(256) void sample_kernel(
    const float* __restrict__ rays_o, const float* __restrict__ rays_d,
    const float* __restrict__ G1, const float* __restrict__ Fg,
    uint4* __restrict__ fvout) {
    const int idx = blockIdx.x * 256 + threadIdx.x;
    const int ray = idx >> 7;
    const int s = idx & 127;

    const float ox = rays_o[ray * 3 + 0], oy = rays_o[ray * 3 + 1], oz = rays_o[ray * 3 + 2];
    const float dx = rays_d[ray * 3 + 0], dy = rays_d[ray * 3 + 1], dz = rays_d[ray * 3 + 2];

    float tnear, tmax;
    ray_aabb(ox, oy, oz, dx, dy, dz, tnear, tmax);
    float t = tnear + (float)s * FSTEP;
    bool maskb = (t < tmax) && (tmax > tnear);

    uint4* op = fvout + (size_t)idx * 4;
    if (!maskb) {
        uint4 z = {0u, 0u, 0u, 0u};
#pragma unroll
        for (int q = 0; q < 4; ++q) op[q] = z;
        return;
    }

    float px = ox + dx * t, py = oy + dy * t, pz = oz + dz * t;
    const float invR = 1.0f / FRADIUS;
    float cx = px * invR, cy = py * invR, cz = pz * invR;

    // G1 trilinear (256^3 x 3)
    float fx = fminf(fmaxf((cx + 1.0f) * 0.5f * 255.0f, 0.0f), 255.0f);
    float fy = fminf(fmaxf((cy + 1.0f) * 0.5f * 255.0f, 0.0f), 255.0f);
    float fz = fminf(fmaxf((cz + 1.0f) * 0.5f * 255.0f, 0.0f), 255.0f);
    float x0f = floorf(fx), y0f = floorf(fy), z0f = floorf(fz);
    float wx = fx - x0f, wy = fy - y0f, wz = fz - z0f;
    int x0 = (int)x0f, y0 = (int)y0f, z0 = (int)z0f;
    int x1 = min(x0 + 1, 255), y1 = min(y0 + 1, 255), z1 = min(z0 + 1, 255);
    float g1x = 0.f, g1y = 0.f, g1z = 0.f;
    {
        float wz0 = 1.f - wz, wy0 = 1.f - wy, wx0 = 1.f - wx;
#pragma unroll
        for (int c = 0; c < 8; ++c) {
            int zz = (c & 4) ? z1 : z0;
            int yy = (c & 2) ? y1 : y0;
            int xx = (c & 1) ? x1 : x0;
            float wgt = ((c & 4) ? wz : wz0) * ((c & 2) ? wy : wy0) * ((c & 1) ? wx : wx0);
            int gidx = (((zz << 8) | yy) << 8 | xx) * 3;
            g1x = fmaf(wgt, G1[gidx + 0], g1x);
            g1y = fmaf(wgt, G1[gidx + 1], g1y);
            g1z = fmaf(wgt, G1[gidx + 2], g1z);
        }
    }

    // Fg trilinear (64^3 x 32)
    float4 fvv[8];
#pragma unroll
    for (int q = 0; q < 8; ++q) fvv[q] = make_float4(0.f, 0.f, 0.f, 0.f);
    {
        float gfx = fminf(fmaxf((g1x + 1.0f) * 0.5f * 63.0f, 0.0f), 63.0f);
        float gfy = fminf(fmaxf((g1y + 1.0f) * 0.5f * 63.0f, 0.0f), 63.0f);
        float gfz = fminf(fmaxf((g1z + 1.0f) * 0.5f * 63.0f, 0.0f), 63.0f);
        float gx0f = floorf(gfx), gy0f = floorf(gfy), gz0f = floorf(gfz);
        float gwx = gfx - gx0f, gwy = gfy - gy0f, gwz = gfz - gz0f;
        int gx0 = (int)gx0f, gy0 = (int)gy0f, gz0 = (int)gz0f;
        int gx1 = min(gx0 + 1, 63), gy1 = min(gy0 + 1, 63), gz1 = min(gz0 + 1, 63);
        float wz0 = 1.f - gwz, wy0 = 1.f - gwy, wx0 = 1.f - gwx;
#pragma unroll
        for (int c = 0; c < 8; ++c) {
            int zz = (c & 4) ? gz1 : gz0;
            int yy = (c & 2) ? gy1 : gy0;
            int xx = (c & 1) ? gx1 : gx0;
            float wgt = ((c & 4) ? gwz : wz0) * ((c & 2) ? gwy : wy0) * ((c & 1) ? gwx : wx0);
            const float4* p = (const float4*)(Fg + (((((zz << 6) | yy) << 6) | xx) << 5));
#pragma unroll
            for (int q = 0; q < 8; ++q) {
                float4 v = p[q];
                fvv[q].x = fmaf(wgt, v.x, fvv[q].x);
                fvv[q].y = fmaf(wgt, v.y, fvv[q].y);
                fvv[q].z = fmaf(wgt, v.z, fvv[q].z);
                fvv[q].w = fmaf(wgt, v.w, fvv[q].w);
            }
        }
    }

#pragma unroll
    for (int q = 0; q < 4; ++q) {
        uint4 u;
        u.x = pk2(fvv[2 * q].x, fvv[2 * q].y);
        u.y = pk2(fvv[2 * q].z, fvv[2 * q].w);
        u.z = pk2(fvv[2 * q + 1].x, fvv[2 * q + 1].y);
        u.w = pk2(fvv[2 * q + 1].z, fvv[2 * q + 1].w);
        op[q] = u;
    }
}

// ---------------- kernel B: MFMA MLP chain + composite (1 block = 1 ray) ----------------
__global__ __launch_bounds__(128) void mlp_kernel(
    const float* __restrict__ rays_o, const float* __restrict__ rays_d,
    const short8* __restrict__ wsf, const short8* __restrict__ fvin,
    float* __restrict__ out) {

    __shared__ __align__(16) __hip_bfloat16 scr[2][32][136];   // activation staging, 272 B stride
    __shared__ __align__(16) __hip_bfloat16 sgm[2][2][16][24]; // raw sig[0..15] per point, 48 B stride
    __shared__ __align__(16) float comp[128][4];               // {alpha, rgb_sigmoid}

    const int ray = blockIdx.x;
    const int tid = threadIdx.x;
    const int w = tid >> 6;
    const int lane = tid & 63;
    const int hi = lane >> 4, lo = lane & 15;

    const float ox = rays_o[ray * 3 + 0], oy = rays_o[ray * 3 + 1], oz = rays_o[ray * 3 + 2];
    const float dx = rays_d[ray * 3 + 0], dy = rays_d[ray * 3 + 1], dz = rays_d[ray * 3 + 2];

    float tnear, tmax;
    ray_aabb(ox, oy, oz, dx, dy, dz, tnear, tmax);
    const bool hit = (tmax > tnear);
    // masked samples are a suffix in s: wave fully masked iff its first sample is masked
    const bool waveDead = !hit || (tnear + (float)(w * 64) * FSTEP >= tmax);

    if (waveDead) {
        float4 z = make_float4(0.f, 0.f, 0.f, 0.f);
        *(float4*)&comp[tid][0] = z;
    } else {
        // SH deg-4 enc (per-ray uniform); lane keeps its k-slice as a B-frag half
        short8 encfrag;
        {
            float inv = rsqrtf(dx * dx + dy * dy + dz * dz);
            float nx = dx * inv, ny = dy * inv, nz = dz * inv;
            float nx2 = nx * nx, ny2 = ny * ny, nz2 = nz * nz;
            float nxy = nx * ny, nyz = ny * nz, nxz = nx * nz;
            float e0 = 0.28209479177387814f;
            float e1 = -0.48860251190291987f * ny;
            float e2 = 0.48860251190291987f * nz;
            float e3 = -0.48860251190291987f * nx;
            float e4 = 1.0925484305920792f * nxy;
            float e5 = -1.0925484305920792f * nyz;
            float e6 = 0.94617469575756f * nz2 - 0.31539156525252f;
            float e7 = -1.0925484305920792f * nxz;
            float e8 = 0.5462742152960396f * (nx2 - ny2);
            float e9 = 0.5900435899266435f * ny * (-3.0f * nx2 + ny2);
            float e10 = 2.890611442640554f * nxy * nz;
            float e11 = 0.4570457994644657f * ny * (1.0f - 5.0f * nz2);
            float e12 = 0.3731763325901154f * nz * (5.0f * nz2 - 3.0f);
            float e13 = 0.4570457994644657f * nx * (1.0f - 5.0f * nz2);
            float e14 = 1.445305721320277f * nz * (nx2 - ny2);
            float e15 = 0.5900435899266435f * nx * (-nx2 + 3.0f * ny2);
            unsigned l0 = pk2(e0, e1), l1 = pk2(e2, e3), l2 = pk2(e4, e5), l3 = pk2(e6, e7);
            unsigned h0 = pk2(e8, e9), h1 = pk2(e10, e11), h2 = pk2(e12, e13), h3 = pk2(e14, e15);
            union { unsigned u[4]; short8 v; } eu;
            eu.u[0] = (hi & 1) ? h0 : l0;
            eu.u[1] = (hi & 1) ? h1 : l1;
            eu.u[2] = (hi & 1) ? h2 : l2;
            eu.u[3] = (hi & 1) ? h3 : l3;
            encfrag = eu.v;
        }
        const bool isEnc = (hi < 2);
        const f32x4 fz4 = {0.f, 0.f, 0.f, 0.f};

        for (int mp = 0; mp < 2; ++mp) {
            const int rbase = mp * 32;

            // s0: 32 -> 128 ; B-frag straight from global ws (1 KB contiguous per wave)
            short8 x0[2];
#pragma unroll
            for (int tt = 0; tt < 2; ++tt) {
                int p = (ray << 7) + w * 64 + rbase + tt * 16 + lo;
                x0[tt] = fvin[p * 4 + hi];
            }
            f32x4 acc[2][8];
#pragma unroll
            for (int tt = 0; tt < 2; ++tt)
#pragma unroll
                for (int nt = 0; nt < 8; ++nt) acc[tt][nt] = fz4;
            {
                short8 wv[8];
#pragma unroll
                for (int nt = 0; nt < 8; ++nt) wv[nt] = wsf[(0 + nt) * 64 + lane];
#pragma unroll
                for (int nt = 0; nt < 8; ++nt)
#pragma unroll
                    for (int tt = 0; tt < 2; ++tt)
                        acc[tt][nt] = MFMA16(wv[nt], x0[tt], acc[tt][nt]);
            }
#pragma unroll
            for (int tt = 0; tt < 2; ++tt)
#pragma unroll
                for (int nt = 0; nt < 8; ++nt) {
                    f32x4 v = acc[tt][nt];
                    uint2 pkv;
                    pkv.x = pk2(fmaxf(v[0], 0.f), fmaxf(v[1], 0.f));
                    pkv.y = pk2(fmaxf(v[2], 0.f), fmaxf(v[3], 0.f));
                    *(uint2*)&scr[w][tt * 16 + lo][nt * 16 + hi * 4] = pkv;
                }

            // s1: 128 -> 128
            f32x4 acc1[2][8];
#pragma unroll
            for (int tt = 0; tt < 2; ++tt)
#pragma unroll
                for (int nt = 0; nt < 8; ++nt) acc1[tt][nt] = fz4;
#pragma unroll
            for (int kt = 0; kt < 4; ++kt) {
                short8 xv[2];
#pragma unroll
                for (int tt = 0; tt < 2; ++tt)
                    xv[tt] = *(const short8*)&scr[w][tt * 16 + lo][kt * 32 + hi * 8];
                short8 wv[8];
#pragma unroll
                for (int nt = 0; nt < 8; ++nt) wv[nt] = wsf[(8 + nt * 4 + kt) * 64 + lane];
#pragma unroll
                for (int nt = 0; nt < 8; ++nt)
#pragma unroll
                    for (int tt = 0; tt < 2; ++tt)
                        acc1[tt][nt] = MFMA16(wv[nt], xv[tt], acc1[tt][nt]);
            }
#pragma unroll
            for (int tt = 0; tt < 2; ++tt)
#pragma unroll
                for (int nt = 0; nt < 8; ++nt) {
                    f32x4 v = acc1[tt][nt];
                    uint2 pkv;
                    pkv.x = pk2(fmaxf(v[0], 0.f), fmaxf(v[1], 0.f));
                    pkv.y = pk2(fmaxf(v[2], 0.f), fmaxf(v[3], 0.f));
                    *(uint2*)&scr[w][tt * 16 + lo][nt * 16 + hi * 4] = pkv;
                }

            // s2: 128 -> 16 (raw outputs)
            f32x4 accS[2];
#pragma unroll
            for (int tt = 0; tt < 2; ++tt) accS[tt] = fz4;
#pragma unroll
            for (int kt = 0; kt < 4; ++kt) {
                short8 xv[2];
#pragma unroll
                for (int tt = 0; tt < 2; ++tt)
                    xv[tt] = *(const short8*)&scr[w][tt * 16 + lo][kt * 32 + hi * 8];
                short8 wv = wsf[(40 + kt) * 64 + lane];
#pragma unroll
                for (int tt = 0; tt < 2; ++tt)
                    accS[tt] = MFMA16(wv, xv[tt], accS[tt]);
            }
            float alphaR[2];
#pragma unroll
            for (int tt = 0; tt < 2; ++tt) {
                f32x4 v = accS[tt];
                uint2 pkv;
                pkv.x = pk2(v[0], v[1]);
                pkv.y = pk2(v[2], v[3]);
                *(uint2*)&sgm[w][tt][lo][hi * 4] = pkv;
                // per-point mask (point index = rbase + tt*16 + lo within this wave's 64)
                float tp = tnear + (float)(w * 64 + rbase + tt * 16 + lo) * FSTEP;
                bool maskp = (tp < tmax);
                float sg = fmaxf(v[0], 0.f);
                alphaR[tt] = maskp ? 1.0f - __expf(-sg * FSTEP) : 0.0f;
            }

            // c0: 32(31) -> 64 ; B-frag = [enc | sig]
            short8 xc[2];
#pragma unroll
            for (int tt = 0; tt < 2; ++tt) {
                short8 sv = *(const short8*)&sgm[w][tt][lo][(hi & 1) * 8];
                xc[tt] = isEnc ? encfrag : sv;
            }
            f32x4 accC[2][4];
#pragma unroll
            for (int tt = 0; tt < 2; ++tt)
#pragma unroll
                for (int nt = 0; nt < 4; ++nt) accC[tt][nt] = fz4;
            {
                short8 wv[4];
#pragma unroll
                for (int nt = 0; nt < 4; ++nt) wv[nt] = wsf[(44 + nt) * 64 + lane];
#pragma unroll
                for (int nt = 0; nt < 4; ++nt)
#pragma unroll
                    for (int tt = 0; tt < 2; ++tt)
                        accC[tt][nt] = MFMA16(wv[nt], xc[tt], accC[tt][nt]);
            }
#pragma unroll
            for (int tt = 0; tt < 2; ++tt)
#pragma unroll
                for (int nt = 0; nt < 4; ++nt) {
                    f32x4 v = accC[tt][nt];
                    uint2 pkv;
                    pkv.x = pk2(fmaxf(v[0], 0.f), fmaxf(v[1], 0.f));
                    pkv.y = pk2(fmaxf(v[2], 0.f), fmaxf(v[3], 0.f));
                    *(uint2*)&scr[w][tt * 16 + lo][nt * 16 + hi * 4] = pkv;
                }

            // c1: 64 -> 64
            f32x4 accD[2][4];
#pragma unroll
            for (int tt = 0; tt < 2; ++tt)
#pragma unroll
                for (int nt = 0; nt < 4; ++nt) accD[tt][nt] = fz4;
#pragma unroll
            for (int kt = 0; kt < 2; ++kt) {
                short8 xv[2];
#pragma unroll
                for (int tt = 0; tt < 2; ++tt)
                    xv[tt] = *(const short8*)&scr[w][tt * 16 + lo][kt * 32 + hi * 8];
                short8 wv[4];
#pragma unroll
                for (int nt = 0; nt < 4; ++nt) wv[nt] = wsf[(48 + nt * 2 + kt) * 64 + lane];
#pragma unroll
                for (int nt = 0; nt < 4; ++nt)
#pragma unroll
                    for (int tt = 0; tt < 2; ++tt)
                        accD[tt][nt] = MFMA16(wv[nt], xv[tt], accD[tt][nt]);
            }
#pragma unroll
            for (int tt = 0; tt < 2; ++tt)
#pragma unroll
                for (int nt = 0; nt < 4; ++nt) {
                    f32x4 v = accD[tt][nt];
                    uint2 pkv;
                    pkv.x = pk2(fmaxf(v[0], 0.f), fmaxf(v[1], 0.f));
                    pkv.y = pk2(fmaxf(v[2], 0.f), fmaxf(v[3], 0.f));
                    *(uint2*)&scr[w][tt * 16 + lo][nt * 16 + hi * 4] = pkv;
                }

            // c2: 64 -> 16(3)
            f32x4 accF[2];
#pragma unroll
            for (int tt = 0; tt < 2; ++tt) accF[tt] = fz4;
#pragma unroll
            for (int kt = 0; kt < 2; ++kt) {
                short8 xv[2];
#pragma unroll
                for (int tt = 0; tt < 2; ++tt)
                    xv[tt] = *(const short8*)&scr[w][tt * 16 + lo][kt * 32 + hi * 8];
                short8 wv = wsf[(56 + kt) * 64 + lane];
#pragma unroll
                for (int tt = 0; tt < 2; ++tt)
                    accF[tt] = MFMA16(wv, xv[tt], accF[tt]);
            }
            if (hi == 0) {
#pragma unroll
                for (int tt = 0; tt < 2; ++tt) {
                    int p = w * 64 + rbase + tt * 16 + lo;
                    f32x4 v = accF[tt];
                    float4 cv;
                    cv.x = alphaR[tt];
                    cv.y = 1.0f / (1.0f + __expf(-v[0]));
                    cv.z = 1.0f / (1.0f + __expf(-v[1]));
                    cv.w = 1.0f / (1.0f + __expf(-v[2]));
                    *(float4*)&comp[p][0] = cv;
                }
            }
        }
    }

    __syncthreads();

    // ---- composite (wave 0: 64-lane scan over 128 samples) ----
    if (tid < 64) {
        const float4* c4 = (const float4*)comp;
        float4 vl = c4[tid];
        float4 vh = c4[tid + 64];
        float a_lo = vl.x, a_hi = vh.x;
        float m_lo = 1.0f - a_lo + 1e-10f;
        float m_hi = 1.0f - a_hi + 1e-10f;

        float p = m_lo;
#pragma unroll
        for (int off = 1; off < 64; off <<= 1) {
            float q = __shfl_up(p, off, 64);
            if (tid >= off) p *= q;
        }
        float ph = m_hi;
#pragma unroll
        for (int off = 1; off < 64; off <<= 1) {
            float q = __shfl_up(ph, off, 64);
            if (tid >= off) ph *= q;
        }
        float total_lo = __shfl(p, 63, 64);
        float e_lo = __shfl_up(p, 1, 64);
        if (tid == 0) e_lo = 1.0f;
        float e_hi = __shfl_up(ph, 1, 64);
        if (tid == 0) e_hi = 1.0f;
        e_hi *= total_lo;

        float w_lo = a_lo * e_lo;
        float w_hi = a_hi * e_hi;

        float sr = w_lo * vl.y + w_hi * vh.y;
        float sg = w_lo * vl.z + w_hi * vh.z;
        float sb = w_lo * vl.w + w_hi * vh.w;
        float sw = w_lo + w_hi;
#pragma unroll
        for (int off = 32; off >= 1; off >>= 1) {
            sr += __shfl_xor(sr, off, 64);
            sg += __shfl_xor(sg, off, 64);
            sb += __shfl_xor(sb, off, 64);
            sw += __shfl_xor(sw, off, 64);
        }
        if (tid == 0) {
            float bg = 1.0f - sw;
            out[ray * 3 + 0] = sr + bg;
            out[ray * 3 + 1] = sg + bg;
            out[ray * 3 + 2] = sb + bg;
        }
    }
}

// ---------------- fallback: validated round-2 fused kernel (used if ws too small) ----------------
__global__ __launch_bounds__(128) void nerf_mfma_kernel(
    const float* __restrict__ rays_o, const float* __restrict__ rays_d,
    const float* __restrict__ G1, const float* __restrict__ Fg,
    const short8* __restrict__ wsf, float* __restrict__ out) {

    __shared__ __align__(16) __hip_bfloat16 fvb[2][64][40];
    __shared__ __align__(16) __hip_bfloat16 scr[2][32][136];
    __shared__ __align__(16) __hip_bfloat16 sgm[2][2][16][24];
    __shared__ __align__(16) float comp[128][4];

    const int ray = blockIdx.x;
    const int tid = threadIdx.x;
    const int w = tid >> 6;
    const int lane = tid & 63;
    const int hi = lane >> 4, lo = lane & 15;
    const int s = tid;

    const float ox = rays_o[ray * 3 + 0], oy = rays_o[ray * 3 + 1], oz = rays_o[ray * 3 + 2];
    const float dx = rays_d[ray * 3 + 0], dy = rays_d[ray * 3 + 1], dz = rays_d[ray * 3 + 2];

    float tnear, tmax;
    ray_aabb(ox, oy, oz, dx, dy, dz, tnear, tmax);
    float t = tnear + (float)s * FSTEP;
    bool maskb = (t < tmax) && (tmax > tnear);

    float px = ox + dx * t, py = oy + dy * t, pz = oz + dz * t;
    const float invR = 1.0f / FRADIUS;
    float cx = px * invR, cy = py * invR, cz = pz * invR;

    float fx = fminf(fmaxf((cx + 1.0f) * 0.5f * 255.0f, 0.0f), 255.0f);
    float fy = fminf(fmaxf((cy + 1.0f) * 0.5f * 255.0f, 0.0f), 255.0f);
    float fz = fminf(fmaxf((cz + 1.0f) * 0.5f * 255.0f, 0.0f), 255.0f);
    float x0f = floorf(fx), y0f = floorf(fy), z0f = floorf(fz);
    float wx = fx - x0f, wy = fy - y0f, wz = fz - z0f;
    int x0 = (int)x0f, y0 = (int)y0f, z0 = (int)z0f;
    int x1 = min(x0 + 1, 255), y1 = min(y0 + 1, 255), z1 = min(z0 + 1, 255);
    float g1x = 0.f, g1y = 0.f, g1z = 0.f;
    {
        float wz0 = 1.f - wz, wy0 = 1.f - wy, wx0 = 1.f - wx;
#pragma unroll
        for (int c = 0; c < 8; ++c) {
            int zz = (c & 4) ? z1 : z0;
            int yy = (c & 2) ? y1 : y0;
            int xx = (c & 1) ? x1 : x0;
            float wgt = ((c & 4) ? wz : wz0) * ((c & 2) ? wy : wy0) * ((c & 1) ? wx : wx0);
            int idx = (((zz << 8) | yy) << 8 | xx) * 3;
            g1x = fmaf(wgt, G1[idx + 0], g1x);
            g1y = fmaf(wgt, G1[idx + 1], g1y);
            g1z = fmaf(wgt, G1[idx + 2], g1z);
        }
    }

    float4 fvv[8];
#pragma unroll
    for (int q = 0; q < 8; ++q) fvv[q] = make_float4(0.f, 0.f, 0.f, 0.f);
    {
        float gfx = fminf(fmaxf((g1x + 1.0f) * 0.5f * 63.0f, 0.0f), 63.0f);
        float gfy = fminf(fmaxf((g1y + 1.0f) * 0.5f * 63.0f, 0.0f), 63.0f);
        float gfz = fminf(fmaxf((g1z + 1.0f) * 0.5f * 63.0f, 0.0f), 63.0f);
        float gx0f = floorf(gfx), gy0f = floorf(gfy), gz0f = floorf(gfz);
        float gwx = gfx - gx0f, gwy = gfy - gy0f, gwz = gfz - gz0f;
        int gx0 = (int)gx0f, gy0 = (int)gy0f, gz0 = (int)gz0f;
        int gx1 = min(gx0 + 1, 63), gy1 = min(gy0 + 1, 63), gz1 = min(gz0 + 1, 63);
        float wz0 = 1.f - gwz, wy0 = 1.f - gwy, wx0 = 1.f - gwx;
#pragma unroll
        for (int c = 0; c < 8; ++c) {
            int zz = (c & 4) ? gz1 : gz0;
            int yy = (c & 2) ? gy1 : gy0;
            int xx = (c & 1) ? gx1 : gx0;
            float wgt = ((c & 4) ? gwz : wz0) * ((c & 2) ? gwy : wy0) * ((c & 1) ? gwx : wx0);
            const float4* p = (const float4*)(Fg + (((((zz << 6) | yy) << 6) | xx) << 5));
#pragma unroll
            for (int q = 0; q < 8; ++q) {
                float4 v = p[q];
                fvv[q].x = fmaf(wgt, v.x, fvv[q].x);
                fvv[q].y = fmaf(wgt, v.y, fvv[q].y);
                fvv[q].z = fmaf(wgt, v.z, fvv[q].z);
                fvv[q].w = fmaf(wgt, v.w, fvv[q].w);
            }
        }
    }

    comp[s][0] = maskb ? 1.0f : 0.0f;

    {
        uint4* rowp = (uint4*)&fvb[w][lane][0];
#pragma unroll
        for (int q = 0; q < 4; ++q) {
            uint4 u;
            u.x = pk2(fvv[2 * q].x, fvv[2 * q].y);
            u.y = pk2(fvv[2 * q].z, fvv[2 * q].w);
            u.z = pk2(fvv[2 * q + 1].x, fvv[2 * q + 1].y);
            u.w = pk2(fvv[2 * q + 1].z, fvv[2 * q + 1].w);
            rowp[q] = u;
        }
    }

    short8 encfrag;
    {
        float inv = rsqrtf(dx * dx + dy * dy + dz * dz);
        float nx = dx * inv, ny = dy * inv, nz = dz * inv;
        float nx2 = nx * nx, ny2 = ny * ny, nz2 = nz * nz;
        float nxy = nx * ny, nyz = ny * nz, nxz = nx * nz;
        float e0 = 0.28209479177387814f;
        float e1 = -0.48860251190291987f * ny;
        float e2 = 0.48860251190291987f * nz;
        float e3 = -0.48860251190291987f * nx;
        float e4 = 1.0925484305920792f * nxy;
        float e5 = -1.0925484305920792f * nyz;
        float e6 = 0.94617469575756f * nz2 - 0.31539156525252f;
        float e7 = -1.0925484305920792f * nxz;
        float e8 = 0.5462742152960396f * (nx2 - ny2);
        float e9 = 0.5900435899266435f * ny * (-3.0f * nx2 + ny2);
        float e10 = 2.890611442640554f * nxy * nz;
        float e11 = 0.4570457994644657f * ny * (1.0f - 5.0f * nz2);
        float e12 = 0.3731763325901154f * nz * (5.0f * nz2 - 3.0f);
        float e13 = 0.4570457994644657f * nx * (1.0f - 5.0f * nz2);
        float e14 = 1.445305721320277f * nz * (nx2 - ny2);
        float e15 = 0.5900435899266435f * nx * (-nx2 + 3.0f * ny2);
        unsigned l0 = pk2(e0, e1), l1 = pk2(e2, e3), l2 = pk2(e4, e5), l3 = pk2(e6, e7);
        unsigned h0 = pk2(e8, e9), h1 = pk2(e10, e11), h2 = pk2(e12, e13), h3 = pk2(e14, e15);
        union { unsigned u[4]; short8 v; } eu;
        eu.u[0] = (hi & 1) ? h0 : l0;
        eu.u[1] = (hi & 1) ? h1 : l1;
        eu.u[2] = (hi & 1) ? h2 : l2;
        eu.u[3] = (hi & 1) ? h3 : l3;
        encfrag = eu.v;
    }
    const bool isEnc = (hi < 2);
    const f32x4 fz4 = {0.f, 0.f, 0.f, 0.f};

    for (int mp = 0; mp < 2; ++mp) {
        const int rbase = mp * 32;

        short8 x0v[2];
#pragma unroll
        for (int tt = 0; tt < 2; ++tt)
            x0v[tt] = *(const short8*)&fvb[w][rbase + tt * 16 + lo][hi * 8];
        f32x4 acc[2][8];
#pragma unroll
        for (int tt = 0; tt < 2; ++tt)
#pragma unroll
            for (int nt = 0; nt < 8; ++nt) acc[tt][nt] = fz4;
        {
            short8 wv[8];
#pragma unroll
            for (int nt = 0; nt < 8; ++nt) wv[nt] = wsf[(0 + nt) * 64 + lane];
#pragma unroll
            for (int nt = 0; nt < 8; ++nt)
#pragma unroll
                for (int tt = 0; tt < 2; ++tt)
                    acc[tt][nt] = MFMA16(wv[nt], x0v[tt], acc[tt][nt]);
        }
#pragma unroll
        for (int tt = 0; tt < 2; ++tt)
#pragma unroll
            for (int nt = 0; nt < 8; ++nt) {
                f32x4 v = acc[tt][nt];
                uint2 pkv;
                pkv.x = pk2(fmaxf(v[0], 0.f), fmaxf(v[1], 0.f));
                pkv.y = pk2(fmaxf(v[2], 0.f), fmaxf(v[3], 0.f));
                *(uint2*)&scr[w][tt * 16 + lo][nt * 16 + hi * 4] = pkv;
            }

        f32x4 acc1[2][8];
#pragma unroll
        for (int tt = 0; tt < 2; ++tt)
#pragma unroll
            for (int nt = 0; nt < 8; ++nt) acc1[tt][nt] = fz4;
#pragma unroll
        for (int kt = 0; kt < 4; ++kt) {
            short8 xv[2];
#pragma unroll
            for (int tt = 0; tt < 2; ++tt)
                xv[tt] = *(const short8*)&scr[w][tt * 16 + lo][kt * 32 + hi * 8];
            short8 wv[8];
#pragma unroll
            for (int nt = 0; nt < 8; ++nt) wv[nt] = wsf[(8 + nt * 4 + kt) * 64 + lane];
#pragma unroll
            for (int nt = 0; nt < 8; ++nt)
#pragma unroll
                for (int tt = 0; tt < 2; ++tt)
                    acc1[tt][nt] = MFMA16(wv[nt], xv[tt], acc1[tt][nt]);
        }
#pragma unroll
        for (int tt = 0; tt < 2; ++tt)
#pragma unroll
            for (int nt = 0; nt < 8; ++nt) {
                f32x4 v = acc1[tt][nt];
                uint2 pkv;
                pkv.x = pk2(fmaxf(v[0], 0.f), fmaxf(v[1], 0.f));
                pkv.y = pk2(fmaxf(v[2], 0.f), fmaxf(v[3], 0.f));
                *(uint2*)&scr[w][tt * 16 + lo][nt * 16 + hi * 4] = pkv;
            }

        f32x4 accS[2];
#pragma unroll
        for (int tt = 0; tt < 2; ++tt) accS[tt] = fz4;
#pragma unroll
        for (int kt = 0; kt < 4; ++kt) {
            short8 xv[2];
#pragma unroll
            for (int tt = 0; tt < 2; ++tt)
                xv[tt] = *(const short8*)&scr[w][tt * 16 + lo][kt * 32 + hi * 8];
            short8 wv = wsf[(40 + kt) * 64 + lane];
#pragma unroll
            for (int tt = 0; tt < 2; ++tt)
                accS[tt] = MFMA16(wv, xv[tt], accS[tt]);
        }
        float alphaR[2];
#pragma unroll
        for (int tt = 0; tt < 2; ++tt) {
            f32x4 v = accS[tt];
            uint2 pkv;
            pkv.x = pk2(v[0], v[1]);
            pkv.y = pk2(v[2], v[3]);
            *(uint2*)&sgm[w][tt][lo][hi * 4] = pkv;
            float mk = comp[w * 64 + rbase + tt * 16 + lo][0];
            float sg = fmaxf(v[0], 0.f);
            alphaR[tt] = (mk != 0.0f) ? 1.0f - __expf(-sg * FSTEP) : 0.0f;
        }

        short8 xc[2];
#pragma unroll
        for (int tt = 0; tt < 2; ++tt) {
            short8 sv = *(const short8*)&sgm[w][tt][lo][(hi & 1) * 8];
            xc[tt] = isEnc ? encfrag : sv;
        }
        f32x4 accC[2][4];
#pragma unroll
        for (int tt = 0; tt < 2; ++tt)
#pragma unroll
            for (int nt = 0; nt < 4; ++nt) accC[tt][nt] = fz4;
        {
            short8 wv[4];
#pragma unroll
            for (int nt = 0; nt < 4; ++nt) wv[nt] = wsf[(44 + nt) * 64 + lane];
#pragma unroll
            for (int nt = 0; nt < 4; ++nt)
#pragma unroll
                for (int tt = 0; tt < 2; ++tt)
                    accC[tt][nt] = MFMA16(wv[nt], xc[tt], accC[tt][nt]);
        }
#pragma unroll
        for (int tt = 0; tt < 2; ++tt)
#pragma unroll
            for (int nt = 0; nt < 4; ++nt) {
                f32x4 v = accC[tt][nt];
                uint2 pkv;
                pkv.x = pk2(fmaxf(v[0], 0.f), fmaxf(v[1], 0.f));
                pkv.y = pk2(fmaxf(v[2], 0.f), fmaxf(v[3], 0.f));
                *(uint2*)&scr[w][tt * 16 + lo][nt * 16 + hi * 4] = pkv;
            }

        f32x4 accD[2][4];
#pragma unroll
        for (int tt = 0; tt < 2; ++tt)
#pragma unroll
            for (int nt = 0; nt < 4; ++nt) accD[tt][nt] = fz4;
#pragma unroll
        for (int kt = 0; kt < 2; ++kt) {
            short8 xv[2];
#pragma unroll
            for (int tt = 0; tt < 2; ++tt)
                xv[tt] = *(const short8*)&scr[w][tt * 16 + lo][kt * 32 + hi * 8];
            short8 wv[4];
#pragma unroll
            for (int nt = 0; nt < 4; ++nt) wv[nt] = wsf[(48 + nt * 2 + kt) * 64 + lane];
#pragma unroll
            for (int nt = 0; nt < 4; ++nt)
#pragma unroll
                for (int tt = 0; tt < 2; ++tt)
                    accD[tt][nt] = MFMA16(wv[nt], xv[tt], accD[tt][nt]);
        }
#pragma unroll
        for (int tt = 0; tt < 2; ++tt)
#pragma unroll
            for (int nt = 0; nt < 4; ++nt) {
                f32x4 v = accD[tt][nt];
                uint2 pkv;
                pkv.x = pk2(fmaxf(v[0], 0.f), fmaxf(v[1], 0.f));
                pkv.y = pk2(fmaxf(v[2], 0.f), fmaxf(v[3], 0.f));
                *(uint2*)&scr[w][tt * 16 + lo][nt * 16 + hi * 4] = pkv;
            }

        f32x4 accF[2];
#pragma unroll
        for (int tt = 0; tt < 2; ++tt) accF[tt] = fz4;
#pragma unroll
        for (int kt = 0; kt < 2; ++kt) {
            short8 xv[2];
#pragma unroll
            for (int tt = 0; tt < 2; ++tt)
                xv[tt] = *(const short8*)&scr[w][tt * 16 + lo][kt * 32 + hi * 8];
            short8 wv = wsf[(56 + kt) * 64 + lane];
#pragma unroll
            for (int tt = 0; tt < 2; ++tt)
                accF[tt] = MFMA16(wv, xv[tt], accF[tt]);
        }
        if (hi == 0) {
#pragma unroll
            for (int tt = 0; tt < 2; ++tt) {
                int p = w * 64 + rbase + tt * 16 + lo;
                f32x4 v = accF[tt];
                float4 cv;
                cv.x = alphaR[tt];
                cv.y = 1.0f / (1.0f + __expf(-v[0]));
                cv.z = 1.0f / (1.0f + __expf(-v[1]));
                cv.w = 1.0f / (1.0f + __expf(-v[2]));
                *(float4*)&comp[p][0] = cv;
            }
        }
    }

    __syncthreads();

    if (tid < 64) {
        const float4* c4 = (const float4*)comp;
        float4 vl = c4[tid];
        float4 vh = c4[tid + 64];
        float a_lo = vl.x, a_hi = vh.x;
        float m_lo = 1.0f - a_lo + 1e-10f;
        float m_hi = 1.0f - a_hi + 1e-10f;

        float p = m_lo;
#pragma unroll
        for (int off = 1; off < 64; off <<= 1) {
            float q = __shfl_up(p, off, 64);
            if (tid >= off) p *= q;
        }
        float ph = m_hi;
#pragma unroll
        for (int off = 1; off < 64; off <<= 1) {
            float q = __shfl_up(ph, off, 64);
            if (tid >= off) ph *= q;
        }
        float total_lo = __shfl(p, 63, 64);
        float e_lo = __shfl_up(p, 1, 64);
        if (tid == 0) e_lo = 1.0f;
        float e_hi = __shfl_up(ph, 1, 64);
        if (tid == 0) e_hi = 1.0f;
        e_hi *= total_lo;

        float w_lo = a_lo * e_lo;
        float w_hi = a_hi * e_hi;

        float sr = w_lo * vl.y + w_hi * vh.y;
        float sg = w_lo * vl.z + w_hi * vh.z;
        float sb = w_lo * vl.w + w_hi * vh.w;
        float sw = w_lo + w_hi;
#pragma unroll
        for (int off = 32; off >= 1; off >>= 1) {
            sr += __shfl_xor(sr, off, 64);
            sg += __shfl_xor(sg, off, 64);
            sb += __shfl_xor(sb, off, 64);
            sw += __shfl_xor(sw, off, 64);
        }
        if (tid == 0) {
            float bg = 1.0f - sw;
            out[ray * 3 + 0] = sr + bg;
            out[ray * 3 + 1] = sg + bg;
            out[ray * 3 + 2] = sb + bg;
        }
    }
}

extern "C" void kernel_launch(void* const* d_in, const int* in_sizes, int n_in,
                              void* d_out, int out_size, void* d_ws, size_t ws_size,
                              hipStream_t stream) {
    const float* rays_o = (const float*)d_in[0];
    const float* rays_d = (const float*)d_in[1];
    const float* G1 = (const float*)d_in[2];
    const float* Fg = (const float*)d_in[3];
    const float* s_w0 = (const float*)d_in[4];
    const float* s_w1 = (const float*)d_in[5];
    const float* s_w2 = (const float*)d_in[6];
    const float* c_w0 = (const float*)d_in[7];
    const float* c_w1 = (const float*)d_in[8];
    const float* c_w2 = (const float*)d_in[9];
    float* out = (float*)d_out;

    const int B = in_sizes[0] / 3;  // 8192 rays
    const int npts = B * 128;

    prep_weights_kernel<<<dim3(58), dim3(64), 0, stream>>>(s_w0, s_w1, s_w2, c_w0, c_w1, c_w2,
                                                           (uint4*)d_ws);

    const size_t FV_OFF = 65536;
    const size_t need = FV_OFF + (size_t)npts * 64;
    if (ws_size >= need) {
        uint4* fv = (uint4*)((char*)d_ws + FV_OFF);
        sample_kernel<<<dim3(npts / 256), dim3(256), 0, stream>>>(rays_o, rays_d, G1, Fg, fv);
        mlp_kernel<<<dim3(B), dim3(128), 0, stream>>>(rays_o, rays_d, (const short8*)d_ws,
                                                      (const short8*)fv, out);
    } else {
        nerf_mfma_kernel<<<dim3(B), dim3(128), 0, stream>>>(
            rays_o, rays_d, G1, Fg, (const short8*)d_ws, out);
    }
}

// Round 4
// 116.667 us; speedup vs baseline: 10.6836x; 1.6131x over previous
//
#include <hip/hip_runtime.h>
#include <hip/hip_bf16.h>

#define FRADIUS 1.3f
#define FSTEP (2.0f * 1.3f / 128.0f)

typedef __attribute__((ext_vector_type(8))) short short8;
typedef __attribute__((ext_vector_type(4))) float f32x4;

#define MFMA16(a, b, c) __builtin_amdgcn_mfma_f32_16x16x32_bf16((a), (b), (c), 0, 0, 0)

// pack two f32 -> bf16x2 in a dword (RNE); low 16 bits = a
__device__ __forceinline__ unsigned pk2(float a, float b) {
    __hip_bfloat162 h = __float22bfloat162_rn(make_float2(a, b));
    union { __hip_bfloat162 h; unsigned u; } cv;
    cv.h = h;
    return cv.u;
}

// shared ray-AABB so all kernels agree bit-exactly
__device__ __forceinline__ void ray_aabb(float ox, float oy, float oz,
                                         float dx, float dy, float dz,
                                         float& tnear, float& tmax) {
    float sdx = (fabsf(dx) < 1e-9f) ? 1e-9f : dx;
    float sdy = (fabsf(dy) < 1e-9f) ? 1e-9f : dy;
    float sdz = (fabsf(dz) < 1e-9f) ? 1e-9f : dz;
    float t1x = (-FRADIUS - ox) / sdx, t2x = (FRADIUS - ox) / sdx;
    float t1y = (-FRADIUS - oy) / sdy, t2y = (FRADIUS - oy) / sdy;
    float t1z = (-FRADIUS - oz) / sdz, t2z = (FRADIUS - oz) / sdz;
    float tmin = fmaxf(fmaxf(fminf(t1x, t2x), fminf(t1y, t2y)), fminf(t1z, t2z));
    tmax = fminf(fminf(fmaxf(t1x, t2x), fmaxf(t1y, t2y)), fmaxf(t1z, t2z));
    tnear = fmaxf(tmin, 0.0f);
}

// ---------------- weight prep: build MFMA A-operand fragments in d_ws ----------------
// frag ids: s0:0..7 (nt,kt=0) | s1:8..39 (nt*4+kt) | s2:40..43 (kt) | c0:44..47 (nt)
//           c1:48..55 (nt*2+kt) | c2:56..57 (kt)
__global__ void prep_weights_kernel(const float* __restrict__ s_w0, const float* __restrict__ s_w1,
                                    const float* __restrict__ s_w2, const float* __restrict__ c_w0,
                                    const float* __restrict__ c_w1, const float* __restrict__ c_w2,
                                    uint4* __restrict__ ws) {
    int fid = blockIdx.x;
    int l = threadIdx.x;
    int hi = l >> 4, lo = l & 15;
    int nt, kt;
    if (fid < 8)       { nt = fid; kt = 0; }
    else if (fid < 40) { int f = fid - 8;  nt = f >> 2; kt = f & 3; }
    else if (fid < 44) { nt = 0; kt = fid - 40; }
    else if (fid < 48) { nt = fid - 44; kt = 0; }
    else if (fid < 56) { int f = fid - 48; nt = f >> 1; kt = f & 1; }
    else               { nt = 0; kt = fid - 56; }
    int n = nt * 16 + lo;
    float v[8];
#pragma unroll
    for (int j = 0; j < 8; ++j) {
        int k = kt * 32 + hi * 8 + j;
        float x;
        if (fid < 8)       x = s_w0[k * 128 + n];
        else if (fid < 40) x = s_w1[k * 128 + n];
        else if (fid < 44) x = s_w2[k * 16 + n];
        else if (fid < 48) x = (k < 16) ? c_w0[k * 64 + n]
                               : ((k == 16) ? 0.0f : c_w0[(k - 1) * 64 + n]);  // zero row: sig[0] unused
        else if (fid < 56) x = c_w1[k * 64 + n];
        else               x = (n < 3) ? c_w2[k * 3 + n] : 0.0f;
        v[j] = x;
    }
    uint4 u;
    u.x = pk2(v[0], v[1]); u.y = pk2(v[2], v[3]);
    u.z = pk2(v[4], v[5]); u.w = pk2(v[6], v[7]);
    ws[fid * 64 + l] = u;
}

// ---------------- kernel A: gather phase (1 thread = 1 sample point) ----------------
__global__ __launch_bounds__(256) void sample_kernel(
    const float* __restrict__ rays_o, const float* __restrict__ rays_d,
    const float* __restrict__ G1, const float* __restrict__ Fg,
    uint4* __restrict__ fvout) {
    const int idx = blockIdx.x * 256 + threadIdx.x;
    const int ray = idx >> 7;
    const int s = idx & 127;

    const float ox = rays_o[ray * 3 + 0], oy = rays_o[ray * 3 + 1], oz = rays_o[ray * 3 + 2];
    const float dx = rays_d[ray * 3 + 0], dy = rays_d[ray * 3 + 1], dz = rays_d[ray * 3 + 2];

    float tnear, tmax;
    ray_aabb(ox, oy, oz, dx, dy, dz, tnear, tmax);
    float t = tnear + (float)s * FSTEP;
    bool maskb = (t < tmax) && (tmax > tnear);

    uint4* op = fvout + (size_t)idx * 4;
    if (!maskb) {
        uint4 z = {0u, 0u, 0u, 0u};
#pragma unroll
        for (int q = 0; q < 4; ++q) op[q] = z;
        return;
    }

    float px = ox + dx * t, py = oy + dy * t, pz = oz + dz * t;
    const float invR = 1.0f / FRADIUS;
    float cx = px * invR, cy = py * invR, cz = pz * invR;

    // G1 trilinear (256^3 x 3)
    float fx = fminf(fmaxf((cx + 1.0f) * 0.5f * 255.0f, 0.0f), 255.0f);
    float fy = fminf(fmaxf((cy + 1.0f) * 0.5f * 255.0f, 0.0f), 255.0f);
    float fz = fminf(fmaxf((cz + 1.0f) * 0.5f * 255.0f, 0.0f), 255.0f);
    float x0f = floorf(fx), y0f = floorf(fy), z0f = floorf(fz);
    float wx = fx - x0f, wy = fy - y0f, wz = fz - z0f;
    int x0 = (int)x0f, y0 = (int)y0f, z0 = (int)z0f;
    int x1 = min(x0 + 1, 255), y1 = min(y0 + 1, 255), z1 = min(z0 + 1, 255);
    float g1x = 0.f, g1y = 0.f, g1z = 0.f;
    {
        float wz0 = 1.f - wz, wy0 = 1.f - wy, wx0 = 1.f - wx;
#pragma unroll
        for (int c = 0; c < 8; ++c) {
            int zz = (c & 4) ? z1 : z0;
            int yy = (c & 2) ? y1 : y0;
            int xx = (c & 1) ? x1 : x0;
            float wgt = ((c & 4) ? wz : wz0) * ((c & 2) ? wy : wy0) * ((c & 1) ? wx : wx0);
            int gidx = (((zz << 8) | yy) << 8 | xx) * 3;
            g1x = fmaf(wgt, G1[gidx + 0], g1x);
            g1y = fmaf(wgt, G1[gidx + 1], g1y);
            g1z = fmaf(wgt, G1[gidx + 2], g1z);
        }
    }

    // Fg trilinear (64^3 x 32)
    float4 fvv[8];
#pragma unroll
    for (int q = 0; q < 8; ++q) fvv[q] = make_float4(0.f, 0.f, 0.f, 0.f);
    {
        float gfx = fminf(fmaxf((g1x + 1.0f) * 0.5f * 63.0f, 0.0f), 63.0f);
        float gfy = fminf(fmaxf((g1y + 1.0f) * 0.5f * 63.0f, 0.0f), 63.0f);
        float gfz = fminf(fmaxf((g1z + 1.0f) * 0.5f * 63.0f, 0.0f), 63.0f);
        float gx0f = floorf(gfx), gy0f = floorf(gfy), gz0f = floorf(gfz);
        float gwx = gfx - gx0f, gwy = gfy - gy0f, gwz = gfz - gz0f;
        int gx0 = (int)gx0f, gy0 = (int)gy0f, gz0 = (int)gz0f;
        int gx1 = min(gx0 + 1, 63), gy1 = min(gy0 + 1, 63), gz1 = min(gz0 + 1, 63);
        float wz0 = 1.f - gwz, wy0 = 1.f - gwy, wx0 = 1.f - gwx;
#pragma unroll
        for (int c = 0; c < 8; ++c) {
            int zz = (c & 4) ? gz1 : gz0;
            int yy = (c & 2) ? gy1 : gy0;
            int xx = (c & 1) ? gx1 : gx0;
            float wgt = ((c & 4) ? gwz : wz0) * ((c & 2) ? gwy : wy0) * ((c & 1) ? gwx : wx0);
            const float4* p = (const float4*)(Fg + (((((zz << 6) | yy) << 6) | xx) << 5));
#pragma unroll
            for (int q = 0; q < 8; ++q) {
                float4 v = p[q];
                fvv[q].x = fmaf(wgt, v.x, fvv[q].x);
                fvv[q].y = fmaf(wgt, v.y, fvv[q].y);
                fvv[q].z = fmaf(wgt, v.z, fvv[q].z);
                fvv[q].w = fmaf(wgt, v.w, fvv[q].w);
            }
        }
    }

#pragma unroll
    for (int q = 0; q < 4; ++q) {
        uint4 u;
        u.x = pk2(fvv[2 * q].x, fvv[2 * q].y);
        u.y = pk2(fvv[2 * q].z, fvv[2 * q].w);
        u.z = pk2(fvv[2 * q + 1].x, fvv[2 * q + 1].y);
        u.w = pk2(fvv[2 * q + 1].z, fvv[2 * q + 1].w);
        op[q] = u;
    }
}

// ---------------- kernel B: MFMA MLP chain; 1 block = 1 wave = 32 samples ----------------
// comp4: per-sample {alpha, sigmoid(rgb)} at comp4[p * cs]   (cs: stride in float4 units)
__global__ __launch_bounds__(64, 4) void mlp_kernel2(
    const float* __restrict__ rays_o, const float* __restrict__ rays_d,
    const short8* __restrict__ wsf, const short8* __restrict__ fvin,
    float4* __restrict__ comp4, int cs) {

    __shared__ __align__(16) __hip_bfloat16 scr[32][136];   // activation staging, 272 B stride
    __shared__ __align__(16) __hip_bfloat16 sgm[2][16][24]; // raw sig[0..15] per point, 48 B stride

    const int ray = blockIdx.x >> 2;
    const int chunk = blockIdx.x & 3;
    const int cbase = chunk * 32;
    const int lane = threadIdx.x;
    const int hi = lane >> 4, lo = lane & 15;

    const float ox = rays_o[ray * 3 + 0], oy = rays_o[ray * 3 + 1], oz = rays_o[ray * 3 + 2];
    const float dx = rays_d[ray * 3 + 0], dy = rays_d[ray * 3 + 1], dz = rays_d[ray * 3 + 2];

    float tnear, tmax;
    ray_aabb(ox, oy, oz, dx, dy, dz, tnear, tmax);
    const bool hit = (tmax > tnear);
    // masked samples form a suffix: chunk fully masked iff its first sample is masked
    const bool dead = !hit || (tnear + (float)cbase * FSTEP >= tmax);

    if (dead) {
        if (lane < 32)
            comp4[(size_t)(ray * 128 + cbase + lane) * cs] = make_float4(0.f, 0.f, 0.f, 0.f);
        return;
    }

    // SH deg-4 enc (per-ray uniform); lane keeps its k-slice as a B-frag half
    short8 encfrag;
    {
        float inv = rsqrtf(dx * dx + dy * dy + dz * dz);
        float nx = dx * inv, ny = dy * inv, nz = dz * inv;
        float nx2 = nx * nx, ny2 = ny * ny, nz2 = nz * nz;
        float nxy = nx * ny, nyz = ny * nz, nxz = nx * nz;
        float e0 = 0.28209479177387814f;
        float e1 = -0.48860251190291987f * ny;
        float e2 = 0.48860251190291987f * nz;
        float e3 = -0.48860251190291987f * nx;
        float e4 = 1.0925484305920792f * nxy;
        float e5 = -1.0925484305920792f * nyz;
        float e6 = 0.94617469575756f * nz2 - 0.31539156525252f;
        float e7 = -1.0925484305920792f * nxz;
        float e8 = 0.5462742152960396f * (nx2 - ny2);
        float e9 = 0.5900435899266435f * ny * (-3.0f * nx2 + ny2);
        float e10 = 2.890611442640554f * nxy * nz;
        float e11 = 0.4570457994644657f * ny * (1.0f - 5.0f * nz2);
        float e12 = 0.3731763325901154f * nz * (5.0f * nz2 - 3.0f);
        float e13 = 0.4570457994644657f * nx * (1.0f - 5.0f * nz2);
        float e14 = 1.445305721320277f * nz * (nx2 - ny2);
        float e15 = 0.5900435899266435f * nx * (-nx2 + 3.0f * ny2);
        unsigned l0 = pk2(e0, e1), l1 = pk2(e2, e3), l2 = pk2(e4, e5), l3 = pk2(e6, e7);
        unsigned h0 = pk2(e8, e9), h1 = pk2(e10, e11), h2 = pk2(e12, e13), h3 = pk2(e14, e15);
        union { unsigned u[4]; short8 v; } eu;
        eu.u[0] = (hi & 1) ? h0 : l0;
        eu.u[1] = (hi & 1) ? h1 : l1;
        eu.u[2] = (hi & 1) ? h2 : l2;
        eu.u[3] = (hi & 1) ? h3 : l3;
        encfrag = eu.v;
    }
    const bool isEnc = (hi < 2);
    const f32x4 fz4 = {0.f, 0.f, 0.f, 0.f};

    // s0: 32 -> 128 ; B-frag straight from global ws (coalesced per wave)
    {
        short8 x0[2];
#pragma unroll
        for (int tt = 0; tt < 2; ++tt) {
            int p = (ray << 7) + cbase + tt * 16 + lo;
            x0[tt] = fvin[p * 4 + hi];
        }
        f32x4 acc[2][8];
#pragma unroll
        for (int tt = 0; tt < 2; ++tt)
#pragma unroll
            for (int nt = 0; nt < 8; ++nt) acc[tt][nt] = fz4;
        {
            short8 wv[8];
#pragma unroll
            for (int nt = 0; nt < 8; ++nt) wv[nt] = wsf[(0 + nt) * 64 + lane];
#pragma unroll
            for (int nt = 0; nt < 8; ++nt)
#pragma unroll
                for (int tt = 0; tt < 2; ++tt)
                    acc[tt][nt] = MFMA16(wv[nt], x0[tt], acc[tt][nt]);
        }
#pragma unroll
        for (int tt = 0; tt < 2; ++tt)
#pragma unroll
            for (int nt = 0; nt < 8; ++nt) {
                f32x4 v = acc[tt][nt];
                uint2 pkv;
                pkv.x = pk2(fmaxf(v[0], 0.f), fmaxf(v[1], 0.f));
                pkv.y = pk2(fmaxf(v[2], 0.f), fmaxf(v[3], 0.f));
                *(uint2*)&scr[tt * 16 + lo][nt * 16 + hi * 4] = pkv;
            }
    }

    // s1: 128 -> 128
    {
        f32x4 acc1[2][8];
#pragma unroll
        for (int tt = 0; tt < 2; ++tt)
#pragma unroll
            for (int nt = 0; nt < 8; ++nt) acc1[tt][nt] = fz4;
#pragma unroll
        for (int kt = 0; kt < 4; ++kt) {
            short8 xv[2];
#pragma unroll
            for (int tt = 0; tt < 2; ++tt)
                xv[tt] = *(const short8*)&scr[tt * 16 + lo][kt * 32 + hi * 8];
            short8 wv[8];
#pragma unroll
            for (int nt = 0; nt < 8; ++nt) wv[nt] = wsf[(8 + nt * 4 + kt) * 64 + lane];
#pragma unroll
            for (int nt = 0; nt < 8; ++nt)
#pragma unroll
                for (int tt = 0; tt < 2; ++tt)
                    acc1[tt][nt] = MFMA16(wv[nt], xv[tt], acc1[tt][nt]);
        }
#pragma unroll
        for (int tt = 0; tt < 2; ++tt)
#pragma unroll
            for (int nt = 0; nt < 8; ++nt) {
                f32x4 v = acc1[tt][nt];
                uint2 pkv;
                pkv.x = pk2(fmaxf(v[0], 0.f), fmaxf(v[1], 0.f));
                pkv.y = pk2(fmaxf(v[2], 0.f), fmaxf(v[3], 0.f));
                *(uint2*)&scr[tt * 16 + lo][nt * 16 + hi * 4] = pkv;
            }
    }

    // s2: 128 -> 16 (raw outputs)
    float alphaR[2];
    {
        f32x4 accS[2];
#pragma unroll
        for (int tt = 0; tt < 2; ++tt) accS[tt] = fz4;
#pragma unroll
        for (int kt = 0; kt < 4; ++kt) {
            short8 xv[2];
#pragma unroll
            for (int tt = 0; tt < 2; ++tt)
                xv[tt] = *(const short8*)&scr[tt * 16 + lo][kt * 32 + hi * 8];
            short8 wv = wsf[(40 + kt) * 64 + lane];
#pragma unroll
            for (int tt = 0; tt < 2; ++tt)
                accS[tt] = MFMA16(wv, xv[tt], accS[tt]);
        }
#pragma unroll
        for (int tt = 0; tt < 2; ++tt) {
            f32x4 v = accS[tt];
            uint2 pkv;
            pkv.x = pk2(v[0], v[1]);
            pkv.y = pk2(v[2], v[3]);
            *(uint2*)&sgm[tt][lo][hi * 4] = pkv;
            float tp = tnear + (float)(cbase + tt * 16 + lo) * FSTEP;
            bool maskp = (tp < tmax);
            float sg = fmaxf(v[0], 0.f);
            alphaR[tt] = maskp ? 1.0f - __expf(-sg * FSTEP) : 0.0f;
        }
    }

    // c0: 32(31) -> 64 ; B-frag = [enc | sig]
    {
        short8 xc[2];
#pragma unroll
        for (int tt = 0; tt < 2; ++tt) {
            short8 sv = *(const short8*)&sgm[tt][lo][(hi & 1) * 8];
            xc[tt] = isEnc ? encfrag : sv;
        }
        f32x4 accC[2][4];
#pragma unroll
        for (int tt = 0; tt < 2; ++tt)
#pragma unroll
            for (int nt = 0; nt < 4; ++nt) accC[tt][nt] = fz4;
        {
            short8 wv[4];
#pragma unroll
            for (int nt = 0; nt < 4; ++nt) wv[nt] = wsf[(44 + nt) * 64 + lane];
#pragma unroll
            for (int nt = 0; nt < 4; ++nt)
#pragma unroll
                for (int tt = 0; tt < 2; ++tt)
                    accC[tt][nt] = MFMA16(wv[nt], xc[tt], accC[tt][nt]);
        }
#pragma unroll
        for (int tt = 0; tt < 2; ++tt)
#pragma unroll
            for (int nt = 0; nt < 4; ++nt) {
                f32x4 v = accC[tt][nt];
                uint2 pkv;
                pkv.x = pk2(fmaxf(v[0], 0.f), fmaxf(v[1], 0.f));
                pkv.y = pk2(fmaxf(v[2], 0.f), fmaxf(v[3], 0.f));
                *(uint2*)&scr[tt * 16 + lo][nt * 16 + hi * 4] = pkv;
            }
    }

    // c1: 64 -> 64
    {
        f32x4 accD[2][4];
#pragma unroll
        for (int tt = 0; tt < 2; ++tt)
#pragma unroll
            for (int nt = 0; nt < 4; ++nt) accD[tt][nt] = fz4;
#pragma unroll
        for (int kt = 0; kt < 2; ++kt) {
            short8 xv[2];
#pragma unroll
            for (int tt = 0; tt < 2; ++tt)
                xv[tt] = *(const short8*)&scr[tt * 16 + lo][kt * 32 + hi * 8];
            short8 wv[4];
#pragma unroll
            for (int nt = 0; nt < 4; ++nt) wv[nt] = wsf[(48 + nt * 2 + kt) * 64 + lane];
#pragma unroll
            for (int nt = 0; nt < 4; ++nt)
#pragma unroll
                for (int tt = 0; tt < 2; ++tt)
                    accD[tt][nt] = MFMA16(wv[nt], xv[tt], accD[tt][nt]);
        }
#pragma unroll
        for (int tt = 0; tt < 2; ++tt)
#pragma unroll
            for (int nt = 0; nt < 4; ++nt) {
                f32x4 v = accD[tt][nt];
                uint2 pkv;
                pkv.x = pk2(fmaxf(v[0], 0.f), fmaxf(v[1], 0.f));
                pkv.y = pk2(fmaxf(v[2], 0.f), fmaxf(v[3], 0.f));
                *(uint2*)&scr[tt * 16 + lo][nt * 16 + hi * 4] = pkv;
            }
    }

    // c2: 64 -> 16(3)
    {
        f32x4 accF[2];
#pragma unroll
        for (int tt = 0; tt < 2; ++tt) accF[tt] = fz4;
#pragma unroll
        for (int kt = 0; kt < 2; ++kt) {
            short8 xv[2];
#pragma unroll
            for (int tt = 0; tt < 2; ++tt)
                xv[tt] = *(const short8*)&scr[tt * 16 + lo][kt * 32 + hi * 8];
            short8 wv = wsf[(56 + kt) * 64 + lane];
#pragma unroll
            for (int tt = 0; tt < 2; ++tt)
                accF[tt] = MFMA16(wv, xv[tt], accF[tt]);
        }
        if (hi == 0) {
#pragma unroll
            for (int tt = 0; tt < 2; ++tt) {
                int p = ray * 128 + cbase + tt * 16 + lo;
                f32x4 v = accF[tt];
                float4 cv;
                cv.x = alphaR[tt];
                cv.y = 1.0f / (1.0f + __expf(-v[0]));
                cv.z = 1.0f / (1.0f + __expf(-v[1]));
                cv.w = 1.0f / (1.0f + __expf(-v[2]));
                comp4[(size_t)p * cs] = cv;
            }
        }
    }
}

// ---------------- kernel C: composite (1 block = 1 ray, 64-lane scan) ----------------
__global__ __launch_bounds__(64) void composite_kernel(
    const float4* __restrict__ comp4, int cs, float* __restrict__ out) {
    const int ray = blockIdx.x;
    const int tid = threadIdx.x;

    float4 vl = comp4[(size_t)(ray * 128 + tid) * cs];
    float4 vh = comp4[(size_t)(ray * 128 + 64 + tid) * cs];
    float a_lo = vl.x, a_hi = vh.x;
    float m_lo = 1.0f - a_lo + 1e-10f;
    float m_hi = 1.0f - a_hi + 1e-10f;

    float p = m_lo;
#pragma unroll
    for (int off = 1; off < 64; off <<= 1) {
        float q = __shfl_up(p, off, 64);
        if (tid >= off) p *= q;
    }
    float ph = m_hi;
#pragma unroll
    for (int off = 1; off < 64; off <<= 1) {
        float q = __shfl_up(ph, off, 64);
        if (tid >= off) ph *= q;
    }
    float total_lo = __shfl(p, 63, 64);
    float e_lo = __shfl_up(p, 1, 64);
    if (tid == 0) e_lo = 1.0f;
    float e_hi = __shfl_up(ph, 1, 64);
    if (tid == 0) e_hi = 1.0f;
    e_hi *= total_lo;

    float w_lo = a_lo * e_lo;
    float w_hi = a_hi * e_hi;

    float sr = w_lo * vl.y + w_hi * vh.y;
    float sg = w_lo * vl.z + w_hi * vh.z;
    float sb = w_lo * vl.w + w_hi * vh.w;
    float sw = w_lo + w_hi;
#pragma unroll
    for (int off = 32; off >= 1; off >>= 1) {
        sr += __shfl_xor(sr, off, 64);
        sg += __shfl_xor(sg, off, 64);
        sb += __shfl_xor(sb, off, 64);
        sw += __shfl_xor(sw, off, 64);
    }
    if (tid == 0) {
        float bg = 1.0f - sw;
        out[ray * 3 + 0] = sr + bg;
        out[ray * 3 + 1] = sg + bg;
        out[ray * 3 + 2] = sb + bg;
    }
}

// ---------------- fallback: validated round-2 fused kernel (used if ws too small) ----------------
__global__ __launch_bounds__(128) void nerf_mfma_kernel(
    const float* __restrict__ rays_o, const float* __restrict__ rays_d,
    const float* __restrict__ G1, const float* __restrict__ Fg,
    const short8* __restrict__ wsf, float* __restrict__ out) {

    __shared__ __align__(16) __hip_bfloat16 fvb[2][64][40];
    __shared__ __align__(16) __hip_bfloat16 scr[2][32][136];
    __shared__ __align__(16) __hip_bfloat16 sgm[2][2][16][24];
    __shared__ __align__(16) float comp[128][4];

    const int ray = blockIdx.x;
    const int tid = threadIdx.x;
    const int w = tid >> 6;
    const int lane = tid & 63;
    const int hi = lane >> 4, lo = lane & 15;
    const int s = tid;

    const float ox = rays_o[ray * 3 + 0], oy = rays_o[ray * 3 + 1], oz = rays_o[ray * 3 + 2];
    const float dx = rays_d[ray * 3 + 0], dy = rays_d[ray * 3 + 1], dz = rays_d[ray * 3 + 2];

    float tnear, tmax;
    ray_aabb(ox, oy, oz, dx, dy, dz, tnear, tmax);
    float t = tnear + (float)s * FSTEP;
    bool maskb = (t < tmax) && (tmax > tnear);

    float px = ox + dx * t, py = oy + dy * t, pz = oz + dz * t;
    const float invR = 1.0f / FRADIUS;
    float cx = px * invR, cy = py * invR, cz = pz * invR;

    float fx = fminf(fmaxf((cx + 1.0f) * 0.5f * 255.0f, 0.0f), 255.0f);
    float fy = fminf(fmaxf((cy + 1.0f) * 0.5f * 255.0f, 0.0f), 255.0f);
    float fz = fminf(fmaxf((cz + 1.0f) * 0.5f * 255.0f, 0.0f), 255.0f);
    float x0f = floorf(fx), y0f = floorf(fy), z0f = floorf(fz);
    float wx = fx - x0f, wy = fy - y0f, wz = fz - z0f;
    int x0 = (int)x0f, y0 = (int)y0f, z0 = (int)z0f;
    int x1 = min(x0 + 1, 255), y1 = min(y0 + 1, 255), z1 = min(z0 + 1, 255);
    float g1x = 0.f, g1y = 0.f, g1z = 0.f;
    {
        float wz0 = 1.f - wz, wy0 = 1.f - wy, wx0 = 1.f - wx;
#pragma unroll
        for (int c = 0; c < 8; ++c) {
            int zz = (c & 4) ? z1 : z0;
            int yy = (c & 2) ? y1 : y0;
            int xx = (c & 1) ? x1 : x0;
            float wgt = ((c & 4) ? wz : wz0) * ((c & 2) ? wy : wy0) * ((c & 1) ? wx : wx0);
            int idx = (((zz << 8) | yy) << 8 | xx) * 3;
            g1x = fmaf(wgt, G1[idx + 0], g1x);
            g1y = fmaf(wgt, G1[idx + 1], g1y);
            g1z = fmaf(wgt, G1[idx + 2], g1z);
        }
    }

    float4 fvv[8];
#pragma unroll
    for (int q = 0; q < 8; ++q) fvv[q] = make_float4(0.f, 0.f, 0.f, 0.f);
    {
        float gfx = fminf(fmaxf((g1x + 1.0f) * 0.5f * 63.0f, 0.0f), 63.0f);
        float gfy = fminf(fmaxf((g1y + 1.0f) * 0.5f * 63.0f, 0.0f), 63.0f);
        float gfz = fminf(fmaxf((g1z + 1.0f) * 0.5f * 63.0f, 0.0f), 63.0f);
        float gx0f = floorf(gfx), gy0f = floorf(gfy), gz0f = floorf(gfz);
        float gwx = gfx - gx0f, gwy = gfy - gy0f, gwz = gfz - gz0f;
        int gx0 = (int)gx0f, gy0 = (int)gy0f, gz0 = (int)gz0f;
        int gx1 = min(gx0 + 1, 63), gy1 = min(gy0 + 1, 63), gz1 = min(gz0 + 1, 63);
        float wz0 = 1.f - gwz, wy0 = 1.f - gwy, wx0 = 1.f - gwx;
#pragma unroll
        for (int c = 0; c < 8; ++c) {
            int zz = (c & 4) ? gz1 : gz0;
            int yy = (c & 2) ? gy1 : gy0;
            int xx = (c & 1) ? gx1 : gx0;
            float wgt = ((c & 4) ? gwz : wz0) * ((c & 2) ? gwy : wy0) * ((c & 1) ? gwx : wx0);
            const float4* p = (const float4*)(Fg + (((((zz << 6) | yy) << 6) | xx) << 5));
#pragma unroll
            for (int q = 0; q < 8; ++q) {
                float4 v = p[q];
                fvv[q].x = fmaf(wgt, v.x, fvv[q].x);
                fvv[q].y = fmaf(wgt, v.y, fvv[q].y);
                fvv[q].z = fmaf(wgt, v.z, fvv[q].z);
                fvv[q].w = fmaf(wgt, v.w, fvv[q].w);
            }
        }
    }

    comp[s][0] = maskb ? 1.0f : 0.0f;

    {
        uint4* rowp = (uint4*)&fvb[w][lane][0];
#pragma unroll
        for (int q = 0; q < 4; ++q) {
            uint4 u;
            u.x = pk2(fvv[2 * q].x, fvv[2 * q].y);
            u.y = pk2(fvv[2 * q].z, fvv[2 * q].w);
            u.z = pk2(fvv[2 * q + 1].x, fvv[2 * q + 1].y);
            u.w = pk2(fvv[2 * q + 1].z, fvv[2 * q + 1].w);
            rowp[q] = u;
        }
    }

    short8 encfrag;
    {
        float inv = rsqrtf(dx * dx + dy * dy + dz * dz);
        float nx = dx * inv, ny = dy * inv, nz = dz * inv;
        float nx2 = nx * nx, ny2 = ny * ny, nz2 = nz * nz;
        float nxy = nx * ny, nyz = ny * nz, nxz = nx * nz;
        float e0 = 0.28209479177387814f;
        float e1 = -0.48860251190291987f * ny;
        float e2 = 0.48860251190291987f * nz;
        float e3 = -0.48860251190291987f * nx;
        float e4 = 1.0925484305920792f * nxy;
        float e5 = -1.0925484305920792f * nyz;
        float e6 = 0.94617469575756f * nz2 - 0.31539156525252f;
        float e7 = -1.0925484305920792f * nxz;
        float e8 = 0.5462742152960396f * (nx2 - ny2);
        float e9 = 0.5900435899266435f * ny * (-3.0f * nx2 + ny2);
        float e10 = 2.890611442640554f * nxy * nz;
        float e11 = 0.4570457994644657f * ny * (1.0f - 5.0f * nz2);
        float e12 = 0.3731763325901154f * nz * (5.0f * nz2 - 3.0f);
        float e13 = 0.4570457994644657f * nx * (1.0f - 5.0f * nz2);
        float e14 = 1.445305721320277f * nz * (nx2 - ny2);
        float e15 = 0.5900435899266435f * nx * (-nx2 + 3.0f * ny2);
        unsigned l0 = pk2(e0, e1), l1 = pk2(e2, e3), l2 = pk2(e4, e5), l3 = pk2(e6, e7);
        unsigned h0 = pk2(e8, e9), h1 = pk2(e10, e11), h2 = pk2(e12, e13), h3 = pk2(e14, e15);
        union { unsigned u[4]; short8 v; } eu;
        eu.u[0] = (hi & 1) ? h0 : l0;
        eu.u[1] = (hi & 1) ? h1 : l1;
        eu.u[2] = (hi & 1) ? h2 : l2;
        eu.u[3] = (hi & 1) ? h3 : l3;
        encfrag = eu.v;
    }
    const bool isEnc = (hi < 2);
    const f32x4 fz4 = {0.f, 0.f, 0.f, 0.f};

    for (int mp = 0; mp < 2; ++mp) {
        const int rbase = mp * 32;

        short8 x0v[2];
#pragma unroll
        for (int tt = 0; tt < 2; ++tt)
            x0v[tt] = *(const short8*)&fvb[w][rbase + tt * 16 + lo][hi * 8];
        f32x4 acc[2][8];
#pragma unroll
        for (int tt = 0; tt < 2; ++tt)
#pragma unroll
            for (int nt = 0; nt < 8; ++nt) acc[tt][nt] = fz4;
        {
            short8 wv[8];
#pragma unroll
            for (int nt = 0; nt < 8; ++nt) wv[nt] = wsf[(0 + nt) * 64 + lane];
#pragma unroll
            for (int nt = 0; nt < 8; ++nt)
#pragma unroll
                for (int tt = 0; tt < 2; ++tt)
                    acc[tt][nt] = MFMA16(wv[nt], x0v[tt], acc[tt][nt]);
        }
#pragma unroll
        for (int tt = 0; tt < 2; ++tt)
#pragma unroll
            for (int nt = 0; nt < 8; ++nt) {
                f32x4 v = acc[tt][nt];
                uint2 pkv;
                pkv.x = pk2(fmaxf(v[0], 0.f), fmaxf(v[1], 0.f));
                pkv.y = pk2(fmaxf(v[2], 0.f), fmaxf(v[3], 0.f));
                *(uint2*)&scr[w][tt * 16 + lo][nt * 16 + hi * 4] = pkv;
            }

        f32x4 acc1[2][8];
#pragma unroll
        for (int tt = 0; tt < 2; ++tt)
#pragma unroll
            for (int nt = 0; nt < 8; ++nt) acc1[tt][nt] = fz4;
#pragma unroll
        for (int kt = 0; kt < 4; ++kt) {
            short8 xv[2];
#pragma unroll
            for (int tt = 0; tt < 2; ++tt)
                xv[tt] = *(const short8*)&scr[w][tt * 16 + lo][kt * 32 + hi * 8];
            short8 wv[8];
#pragma unroll
            for (int nt = 0; nt < 8; ++nt) wv[nt] = wsf[(8 + nt * 4 + kt) * 64 + lane];
#pragma unroll
            for (int nt = 0; nt < 8; ++nt)
#pragma unroll
                for (int tt = 0; tt < 2; ++tt)
                    acc1[tt][nt] = MFMA16(wv[nt], xv[tt], acc1[tt][nt]);
        }
#pragma unroll
        for (int tt = 0; tt < 2; ++tt)
#pragma unroll
            for (int nt = 0; nt < 8; ++nt) {
                f32x4 v = acc1[tt][nt];
                uint2 pkv;
                pkv.x = pk2(fmaxf(v[0], 0.f), fmaxf(v[1], 0.f));
                pkv.y = pk2(fmaxf(v[2], 0.f), fmaxf(v[3], 0.f));
                *(uint2*)&scr[w][tt * 16 + lo][nt * 16 + hi * 4] = pkv;
            }

        f32x4 accS[2];
#pragma unroll
        for (int tt = 0; tt < 2; ++tt) accS[tt] = fz4;
#pragma unroll
        for (int kt = 0; kt < 4; ++kt) {
            short8 xv[2];
#pragma unroll
            for (int tt = 0; tt < 2; ++tt)
                xv[tt] = *(const short8*)&scr[w][tt * 16 + lo][kt * 32 + hi * 8];
            short8 wv = wsf[(40 + kt) * 64 + lane];
#pragma unroll
            for (int tt = 0; tt < 2; ++tt)
                accS[tt] = MFMA16(wv, xv[tt], accS[tt]);
        }
        float alphaR[2];
#pragma unroll
        for (int tt = 0; tt < 2; ++tt) {
            f32x4 v = accS[tt];
            uint2 pkv;
            pkv.x = pk2(v[0], v[1]);
            pkv.y = pk2(v[2], v[3]);
            *(uint2*)&sgm[w][tt][lo][hi * 4] = pkv;
            float mk = comp[w * 64 + rbase + tt * 16 + lo][0];
            float sg = fmaxf(v[0], 0.f);
            alphaR[tt] = (mk != 0.0f) ? 1.0f - __expf(-sg * FSTEP) : 0.0f;
        }

        short8 xc[2];
#pragma unroll
        for (int tt = 0; tt < 2; ++tt) {
            short8 sv = *(const short8*)&sgm[w][tt][lo][(hi & 1) * 8];
            xc[tt] = isEnc ? encfrag : sv;
        }
        f32x4 accC[2][4];
#pragma unroll
        for (int tt = 0; tt < 2; ++tt)
#pragma unroll
            for (int nt = 0; nt < 4; ++nt) accC[tt][nt] = fz4;
        {
            short8 wv[4];
#pragma unroll
            for (int nt = 0; nt < 4; ++nt) wv[nt] = wsf[(44 + nt) * 64 + lane];
#pragma unroll
            for (int nt = 0; nt < 4; ++nt)
#pragma unroll
                for (int tt = 0; tt < 2; ++tt)
                    accC[tt][nt] = MFMA16(wv[nt], xc[tt], accC[tt][nt]);
        }
#pragma unroll
        for (int tt = 0; tt < 2; ++tt)
#pragma unroll
            for (int nt = 0; nt < 4; ++nt) {
                f32x4 v = accC[tt][nt];
                uint2 pkv;
                pkv.x = pk2(fmaxf(v[0], 0.f), fmaxf(v[1], 0.f));
                pkv.y = pk2(fmaxf(v[2], 0.f), fmaxf(v[3], 0.f));
                *(uint2*)&scr[w][tt * 16 + lo][nt * 16 + hi * 4] = pkv;
            }

        f32x4 accD[2][4];
#pragma unroll
        for (int tt = 0; tt < 2; ++tt)
#pragma unroll
            for (int nt = 0; nt < 4; ++nt) accD[tt][nt] = fz4;
#pragma unroll
        for (int kt = 0; kt < 2; ++kt) {
            short8 xv[2];
#pragma unroll
            for (int tt = 0; tt < 2; ++tt)
                xv[tt] = *(const short8*)&scr[w][tt * 16 + lo][kt * 32 + hi * 8];
            short8 wv[4];
#pragma unroll
            for (int nt = 0; nt < 4; ++nt) wv[nt] = wsf[(48 + nt * 2 + kt) * 64 + lane];
#pragma unroll
            for (int nt = 0; nt < 4; ++nt)
#pragma unroll
                for (int tt = 0; tt < 2; ++tt)
                    accD[tt][nt] = MFMA16(wv[nt], xv[tt], accD[tt][nt]);
        }
#pragma unroll
        for (int tt = 0; tt < 2; ++tt)
#pragma unroll
            for (int nt = 0; nt < 4; ++nt) {
                f32x4 v = accD[tt][nt];
                uint2 pkv;
                pkv.x = pk2(fmaxf(v[0], 0.f), fmaxf(v[1], 0.f));
                pkv.y = pk2(fmaxf(v[2], 0.f), fmaxf(v[3], 0.f));
                *(uint2*)&scr[w][tt * 16 + lo][nt * 16 + hi * 4] = pkv;
            }

        f32x4 accF[2];
#pragma unroll
        for (int tt = 0; tt < 2; ++tt) accF[tt] = fz4;
#pragma unroll
        for (int kt = 0; kt < 2; ++kt) {
            short8 xv[2];
#pragma unroll
            for (int tt = 0; tt < 2; ++tt)
                xv[tt] = *(const short8*)&scr[w][tt * 16 + lo][kt * 32 + hi * 8];
            short8 wv = wsf[(56 + kt) * 64 + lane];
#pragma unroll
            for (int tt = 0; tt < 2; ++tt)
                accF[tt] = MFMA16(wv, xv[tt], accF[tt]);
        }
        if (hi == 0) {
#pragma unroll
            for (int tt = 0; tt < 2; ++tt) {
                int p = w * 64 + rbase + tt * 16 + lo;
                f32x4 v = accF[tt];
                float4 cv;
                cv.x = alphaR[tt];
                cv.y = 1.0f / (1.0f + __expf(-v[0]));
                cv.z = 1.0f / (1.0f + __expf(-v[1]));
                cv.w = 1.0f / (1.0f + __expf(-v[2]));
                *(float4*)&comp[p][0] = cv;
            }
        }
    }

    __syncthreads();

    if (tid < 64) {
        const float4* c4 = (const float4*)comp;
        float4 vl = c4[tid];
        float4 vh = c4[tid + 64];
        float a_lo = vl.x, a_hi = vh.x;
        float m_lo = 1.0f - a_lo + 1e-10f;
        float m_hi = 1.0f - a_hi + 1e-10f;

        float p = m_lo;
#pragma unroll
        for (int off = 1; off < 64; off <<= 1) {
            float q = __shfl_up(p, off, 64);
            if (tid >= off) p *= q;
        }
        float ph = m_hi;
#pragma unroll
        for (int off = 1; off < 64; off <<= 1) {
            float q = __shfl_up(ph, off, 64);
            if (tid >= off) ph *= q;
        }
        float total_lo = __shfl(p, 63, 64);
        float e_lo = __shfl_up(p, 1, 64);
        if (tid == 0) e_lo = 1.0f;
        float e_hi = __shfl_up(ph, 1, 64);
        if (tid == 0) e_hi = 1.0f;
        e_hi *= total_lo;

        float w_lo = a_lo * e_lo;
        float w_hi = a_hi * e_hi;

        float sr = w_lo * vl.y + w_hi * vh.y;
        float sg = w_lo * vl.z + w_hi * vh.z;
        float sb = w_lo * vl.w + w_hi * vh.w;
        float sw = w_lo + w_hi;
#pragma unroll
        for (int off = 32; off >= 1; off >>= 1) {
            sr += __shfl_xor(sr, off, 64);
            sg += __shfl_xor(sg, off, 64);
            sb += __shfl_xor(sb, off, 64);
            sw += __shfl_xor(sw, off, 64);
        }
        if (tid == 0) {
            float bg = 1.0f - sw;
            out[ray * 3 + 0] = sr + bg;
            out[ray * 3 + 1] = sg + bg;
            out[ray * 3 + 2] = sb + bg;
        }
    }
}

extern "C" void kernel_launch(void* const* d_in, const int* in_sizes, int n_in,
                              void* d_out, int out_size, void* d_ws, size_t ws_size,
                              hipStream_t stream) {
    const float* rays_o = (const float*)d_in[0];
    const float* rays_d = (const float*)d_in[1];
    const float* G1 = (const float*)d_in[2];
    const float* Fg = (const float*)d_in[3];
    const float* s_w0 = (const float*)d_in[4];
    const float* s_w1 = (const float*)d_in[5];
    const float* s_w2 = (const float*)d_in[6];
    const float* c_w0 = (const float*)d_in[7];
    const float* c_w1 = (const float*)d_in[8];
    const float* c_w2 = (const float*)d_in[9];
    float* out = (float*)d_out;

    const int B = in_sizes[0] / 3;  // 8192 rays
    const int npts = B * 128;

    prep_weights_kernel<<<dim3(58), dim3(64), 0, stream>>>(s_w0, s_w1, s_w2, c_w0, c_w1, c_w2,
                                                           (uint4*)d_ws);

    const size_t FV_OFF = 65536;
    const size_t fv_bytes = (size_t)npts * 64;
    const size_t need_split = FV_OFF + fv_bytes;
    const size_t need_full = need_split + (size_t)npts * 16;

    if (ws_size >= need_split) {
        uint4* fv = (uint4*)((char*)d_ws + FV_OFF);
        // comp buffer: separate region if it fits, else alias into fv (stride 64 B; safe:
        // each wave fully consumes its samples' fv at layer s0 before writing comp at c2)
        float4* comp4;
        int cs;
        if (ws_size >= need_full) {
            comp4 = (float4*)((char*)d_ws + need_split);
            cs = 1;
        } else {
            comp4 = (float4*)fv;
            cs = 4;
        }
        sample_kernel<<<dim3(npts / 256), dim3(256), 0, stream>>>(rays_o, rays_d, G1, Fg, fv);
        mlp_kernel2<<<dim3(B * 4), dim3(64), 0, stream>>>(rays_o, rays_d, (const short8*)d_ws,
                                                          (const short8*)fv, comp4, cs);
        composite_kernel<<<dim3(B), dim3(64), 0, stream>>>(comp4, cs, out);
    } else {
        nerf_mfma_kernel<<<dim3(B), dim3(128), 0, stream>>>(
            rays_o, rays_d, G1, Fg, (const short8*)d_ws, out);
    }
}